// Round 15
// baseline (2413.922 us; speedup 1.0000x reference)
//
#include <hip/hip_runtime.h>
#include <hip/hip_bf16.h>
#include <math.h>

#define DEV __device__ __forceinline__

typedef __attribute__((ext_vector_type(4))) float floatx4;
typedef __attribute__((ext_vector_type(8))) __bf16 bf16x8;

static constexpr int A_ = 64, T_ = 50, K_ = 6, H_ = 128, NH_ = 8, F_ = 60, L_ = 512;
static constexpr int M_  = A_ * T_ * K_;   // 19200 mode nodes
static constexpr int AT_ = A_ * T_;        // 3200
static constexpr int FF_ = 4 * H_;         // 512
static constexpr int NL_ = 10;
static constexpr int P2F = 2 * F_;         // 120
static constexpr int AK_ = A_ * K_;        // 384
static constexpr size_t WLAY = 196608;     // per-layer transposed-weight elems
static constexpr int NB_ = (M_ + 255) / 256;  // 75 blocks for M-sized grids

// ---- bf16 split helpers ----
DEV ushort f2bh(float f) {                 // RNE float->bf16 bits
    unsigned u = __float_as_uint(f);
    unsigned r = u + 0x7FFFu + ((u >> 16) & 1u);
    return (ushort)(r >> 16);
}
DEV float bh2f(ushort h) { return __uint_as_float(((unsigned)h) << 16); }

// ============ ln_stats: per-row mean / rsqrt(var+eps), one wave per row ====
__global__ __launch_bounds__(256) void ln_stats(const float* __restrict__ x,
                                                float* __restrict__ mu,
                                                float* __restrict__ rs, int n) {
    int row = blockIdx.x * 4 + (threadIdx.x >> 6);
    int lane = threadIdx.x & 63;
    if (row >= n) return;
    const float* xr = x + (size_t)row * H_;
    float v0 = xr[lane], v1 = xr[lane + 64];
    float s = v0 + v1;
    for (int m = 32; m >= 1; m >>= 1) s += __shfl_xor(s, m, 64);
    float m_ = s * (1.f / 128.f);
    float d0 = v0 - m_, d1 = v1 - m_;
    float vs = d0 * d0 + d1 * d1;
    for (int m = 32; m >= 1; m >>= 1) vs += __shfl_xor(vs, m, 64);
    if (lane == 0) {
        mu[row] = m_;
        rs[row] = rsqrtf(vs * (1.f / 128.f) + 1e-5f);
    }
}

// ====== split-bf16 MFMA GEMM: Y = act(LN?(X) @ W + bias) (+res) ===========
// OMODE: 0 = f32 out (+RES), 1 = bf16 out, 2 = mixed (col-block 0 -> f32 Y
// stride 128; col-blocks 1,2 -> bf16 Yb stride 256). LNX: apply layernorm
// during staging (Kd==128). STATS: emit per-row mu/rs of the final output
// (requires OMODE 0, C==128, single col-block).
template <int ACT, bool RES, int OMODE, bool LNX, bool STATS>
__global__ __launch_bounds__(256) void mgemm(const float* __restrict__ X,
                                             const ushort* __restrict__ Wh,
                                             const ushort* __restrict__ Wl,
                                             const float* __restrict__ bias,
                                             const float* __restrict__ res,
                                             float* __restrict__ Y,
                                             ushort* __restrict__ Yb,
                                             const float* __restrict__ muv,
                                             const float* __restrict__ rsv,
                                             const float* __restrict__ lng,
                                             const float* __restrict__ lnb,
                                             float* __restrict__ muo,
                                             float* __restrict__ rso,
                                             int n, int Kd, int C) {
    __shared__ ushort lds[4 * 8192];           // Xh,Xl,Wsh,Wsl: [128][64] each
    ushort* Xh  = lds;
    ushort* Xl  = lds + 8192;
    ushort* Wsh = lds + 16384;
    ushort* Wsl = lds + 24576;
    int row0 = blockIdx.x * 128, col0 = blockIdx.y * 128;
    int tid = threadIdx.x;
    int lane = tid & 63, wid = tid >> 6;
    int rbase = (wid >> 1) * 64, cbase = (wid & 1) * 64;
    int lrow = lane & 15, lk = lane >> 4;
    floatx4 acc[4][4];
#pragma unroll
    for (int a = 0; a < 4; a++)
#pragma unroll
        for (int b2 = 0; b2 < 4; b2++) acc[a][b2] = floatx4{0.f, 0.f, 0.f, 0.f};

    for (int k0 = 0; k0 < Kd; k0 += 64) {
        float4 g4, b4;
        if (LNX) {
            int kcol = k0 + (tid & 15) * 4;
            g4 = *(const float4*)(lng + kcol);
            b4 = *(const float4*)(lnb + kcol);
        }
#pragma unroll
        for (int i = 0; i < 8; i++) {
            int idx = tid + i * 256;
            int r = idx >> 4, kc = idx & 15;
            float4 v = *(const float4*)(X + (size_t)(row0 + r) * Kd + k0 + kc * 4);
            if (LNX) {
                float mur = muv[row0 + r];
                float rsr = rsv[row0 + r];
                v.x = (v.x - mur) * rsr * g4.x + b4.x;
                v.y = (v.y - mur) * rsr * g4.y + b4.y;
                v.z = (v.z - mur) * rsr * g4.z + b4.z;
                v.w = (v.w - mur) * rsr * g4.w + b4.w;
            }
            ushort h0 = f2bh(v.x), h1 = f2bh(v.y), h2 = f2bh(v.z), h3 = f2bh(v.w);
            ushort l0 = f2bh(v.x - bh2f(h0)), l1 = f2bh(v.y - bh2f(h1)),
                   l2 = f2bh(v.z - bh2f(h2)), l3 = f2bh(v.w - bh2f(h3));
            int base = (r << 6) + (((kc >> 1) ^ (r & 7)) << 3) + ((kc & 1) << 2);
            *(ushort4*)(Xh + base) = make_ushort4(h0, h1, h2, h3);
            *(ushort4*)(Xl + base) = make_ushort4(l0, l1, l2, l3);
        }
#pragma unroll
        for (int i = 0; i < 4; i++) {
            int idx = tid + i * 256;
            int c = idx >> 3, ch = idx & 7;
            int base = (c << 6) + ((ch ^ (c & 7)) << 3);
            size_t go = (size_t)(col0 + c) * Kd + k0 + ch * 8;
            *(float4*)(Wsh + base) = *(const float4*)(Wh + go);
            *(float4*)(Wsl + base) = *(const float4*)(Wl + go);
        }
        __syncthreads();
#pragma unroll
        for (int kk = 0; kk < 2; kk++) {
            int ch = kk * 4 + lk;
            bf16x8 xh[4], xl[4], wh[4], wl[4];
#pragma unroll
            for (int s = 0; s < 4; s++) {
                int r = rbase + s * 16 + lrow;
                int xoff = (r << 6) + ((ch ^ (r & 7)) << 3);
                xh[s] = *(const bf16x8*)(Xh + xoff);
                xl[s] = *(const bf16x8*)(Xl + xoff);
                int c = cbase + s * 16 + lrow;
                int woff = (c << 6) + ((ch ^ (c & 7)) << 3);
                wh[s] = *(const bf16x8*)(Wsh + woff);
                wl[s] = *(const bf16x8*)(Wsl + woff);
            }
#pragma unroll
            for (int sr = 0; sr < 4; sr++)
#pragma unroll
                for (int sc = 0; sc < 4; sc++) {
                    acc[sr][sc] = __builtin_amdgcn_mfma_f32_16x16x32_bf16(wh[sc], xh[sr], acc[sr][sc], 0, 0, 0);
                    acc[sr][sc] = __builtin_amdgcn_mfma_f32_16x16x32_bf16(wl[sc], xh[sr], acc[sr][sc], 0, 0, 0);
                    acc[sr][sc] = __builtin_amdgcn_mfma_f32_16x16x32_bf16(wh[sc], xl[sr], acc[sr][sc], 0, 0, 0);
                }
        }
        __syncthreads();
    }
    float rowsum[4] = {}, rowsq[4] = {};
#pragma unroll
    for (int sr = 0; sr < 4; sr++) {
        int row = row0 + rbase + sr * 16 + lrow;
#pragma unroll
        for (int sc = 0; sc < 4; sc++) {
            int col = col0 + cbase + sc * 16 + lk * 4;
            float4 v = make_float4(acc[sr][sc][0], acc[sr][sc][1],
                                   acc[sr][sc][2], acc[sr][sc][3]);
            if (bias) { float4 bv = *(const float4*)(bias + col);
                        v.x += bv.x; v.y += bv.y; v.z += bv.z; v.w += bv.w; }
            if (ACT == 1) { v.x = fmaxf(v.x, 0.f); v.y = fmaxf(v.y, 0.f);
                            v.z = fmaxf(v.z, 0.f); v.w = fmaxf(v.w, 0.f); }
            if (OMODE == 0) {
                size_t o = (size_t)row * C + col;
                if (RES) { float4 rv = *(const float4*)(res + o);
                           v.x += rv.x; v.y += rv.y; v.z += rv.z; v.w += rv.w; }
                if (STATS) {
                    rowsum[sr] += v.x + v.y + v.z + v.w;
                    rowsq[sr]  += v.x * v.x + v.y * v.y + v.z * v.z + v.w * v.w;
                }
                *(float4*)(Y + o) = v;
            } else if (OMODE == 1) {
                size_t o = (size_t)row * C + col;
                *(ushort4*)(Yb + o) = make_ushort4(f2bh(v.x), f2bh(v.y), f2bh(v.z), f2bh(v.w));
            } else {
                if (col0 == 0) {
                    *(float4*)(Y + (size_t)row * 128 + col) = v;
                } else {
                    *(ushort4*)(Yb + (size_t)row * 256 + (col - 128)) =
                        make_ushort4(f2bh(v.x), f2bh(v.y), f2bh(v.z), f2bh(v.w));
                }
            }
        }
    }
    if (STATS) {
        float* sums = (float*)lds;            // [128][8]
        float* sqs  = ((float*)lds) + 1024;   // [128][8]
        int slot = (wid & 1) * 4 + lk;
#pragma unroll
        for (int sr = 0; sr < 4; sr++) {
            int rl = rbase + sr * 16 + lrow;
            sums[rl * 8 + slot] = rowsum[sr];
            sqs[rl * 8 + slot]  = rowsq[sr];
        }
        __syncthreads();
        if (tid < 128) {
            float s = 0.f, sq = 0.f;
#pragma unroll
            for (int t = 0; t < 8; t++) { s += sums[tid * 8 + t]; sq += sqs[tid * 8 + t]; }
            float mu = s * (1.f / 128.f);
            float var = sq * (1.f / 128.f) - mu * mu;
            muo[row0 + tid] = mu;
            rso[row0 + tid] = rsqrtf(var + 1e-5f);
        }
    }
}

// ==== prep_w: transpose+split all per-layer GEMM weights to bf16 [C][K] ====
__global__ __launch_bounds__(256) void prep_w(const float* __restrict__ Wq,
                                              const float* __restrict__ Wk,
                                              const float* __restrict__ Wv,
                                              const float* __restrict__ Wo,
                                              const float* __restrict__ fW1,
                                              const float* __restrict__ fW2,
                                              ushort* __restrict__ oh,
                                              ushort* __restrict__ ol) {
    int l = blockIdx.y, t = blockIdx.x;
    const float* src; int K, C, tiles_c; size_t obase;
    if (t < 64) {
        int mi = t >> 4; t &= 15;
        src = (mi == 0 ? Wq : mi == 1 ? Wk : mi == 2 ? Wv : Wo) + (size_t)l * 16384;
        K = 128; C = 128; tiles_c = 4; obase = (size_t)l * WLAY + (size_t)mi * 16384;
    } else if (t < 128) {
        t -= 64; src = fW1 + (size_t)l * 65536;
        K = 128; C = 512; tiles_c = 16; obase = (size_t)l * WLAY + 65536;
    } else {
        t -= 128; src = fW2 + (size_t)l * 65536;
        K = 512; C = 128; tiles_c = 4; obase = (size_t)l * WLAY + 131072;
    }
    int tc = t % tiles_c, tk = t / tiles_c;
    __shared__ float tile[32][33];
    int tx = threadIdx.x & 31, ty = threadIdx.x >> 5;
#pragma unroll
    for (int i = 0; i < 4; i++) {
        int k = tk * 32 + ty + i * 8;
        tile[ty + i * 8][tx] = src[(size_t)k * C + tc * 32 + tx];
    }
    __syncthreads();
#pragma unroll
    for (int i = 0; i < 4; i++) {
        int c = tc * 32 + ty + i * 8;
        float v = tile[tx][ty + i * 8];
        ushort h = f2bh(v);
        ushort lo = f2bh(v - bh2f(h));
        size_t o = obase + (size_t)c * K + tk * 32 + tx;
        oh[o] = h; ol[o] = lo;
    }
}

// ============== naive GEMM for small/ragged shapes =========================
template <int ACT, bool RES>
__global__ void small_gemm(const float* __restrict__ X, const float* __restrict__ W,
                           const float* __restrict__ bias, const float* __restrict__ res,
                           float* __restrict__ Y, int n, int Kd, int C) {
    int idx = blockIdx.x * 256 + threadIdx.x;
    if (idx >= n * C) return;
    int row = idx / C, c = idx - row * C;
    float a = bias ? bias[c] : 0.f;
    const float* xr = X + (size_t)row * Kd;
    for (int k = 0; k < Kd; k++) a = fmaf(xr[k], W[(size_t)k * C + c], a);
    if (ACT == 1) a = fmaxf(a, 0.f);
    if (RES) a += res[idx];
    Y[idx] = a;
}

// ==== combined weights cW[l][k][c256]: tiled f32 GEMM, 16 blocks ===========
__global__ __launch_bounds__(256) void combine_fast(const float* __restrict__ eW2,
                                                    const float* __restrict__ Wke,
                                                    const float* __restrict__ Wve,
                                                    float* __restrict__ cW) {
    __shared__ float Xs[128 * 36];
    __shared__ float Ws[32 * 128];
    int x = blockIdx.x;
    int li = x & 7, kv = x >> 3;
    int l = li < 4 ? li : li + 1;
    int g = (li & 3) + 1;
    const float* E2 = eW2 + (size_t)g * 16384;
    const float* Wp = (kv ? Wve : Wke) + (size_t)l * 16384;
    float* out = cW + (size_t)l * 32768 + kv * 128;
    int tid = threadIdx.x;
    int tc = tid & 15, tr = tid >> 4;
    int cA = tc * 4, rA = tr * 4;
    float acc[8][8] = {};
    for (int j0 = 0; j0 < 128; j0 += 32) {
#pragma unroll
        for (int i = 0; i < 4; i++) {
            int idx = tid + i * 256;
            int r = idx >> 3, jc = idx & 7;
            *(float4*)(Xs + r * 36 + jc * 4) =
                *(const float4*)(E2 + (size_t)r * 128 + j0 + jc * 4);
        }
#pragma unroll
        for (int i = 0; i < 4; i++) {
            int idx = tid + i * 256;
            int cc = idx & 31, jj = idx >> 5;
            *(float4*)(Ws + jj * 128 + cc * 4) =
                *(const float4*)(Wp + (size_t)(j0 + jj) * 128 + cc * 4);
        }
        __syncthreads();
#pragma unroll 8
        for (int jj = 0; jj < 32; jj++) {
            float4 w0 = *(const float4*)(Ws + jj * 128 + cA);
            float4 w1 = *(const float4*)(Ws + jj * 128 + cA + 64);
            float xr[8];
#pragma unroll
            for (int i2 = 0; i2 < 4; i2++) {
                xr[i2]     = Xs[(rA + i2) * 36 + jj];
                xr[4 + i2] = Xs[(rA + i2 + 64) * 36 + jj];
            }
#pragma unroll
            for (int i2 = 0; i2 < 8; i2++) {
                float xv = xr[i2];
                acc[i2][0] = fmaf(xv, w0.x, acc[i2][0]);
                acc[i2][1] = fmaf(xv, w0.y, acc[i2][1]);
                acc[i2][2] = fmaf(xv, w0.z, acc[i2][2]);
                acc[i2][3] = fmaf(xv, w0.w, acc[i2][3]);
                acc[i2][4] = fmaf(xv, w1.x, acc[i2][4]);
                acc[i2][5] = fmaf(xv, w1.y, acc[i2][5]);
                acc[i2][6] = fmaf(xv, w1.z, acc[i2][6]);
                acc[i2][7] = fmaf(xv, w1.w, acc[i2][7]);
            }
        }
        __syncthreads();
    }
#pragma unroll
    for (int i = 0; i < 8; i++) {
        int r = (i < 4) ? (rA + i) : (rA + i + 60);
#pragma unroll
        for (int chh = 0; chh < 2; chh++) {
            int c = cA + chh * 64;
            *(float4*)(out + (size_t)r * 256 + c) =
                make_float4(acc[i][chh * 4 + 0], acc[i][chh * 4 + 1],
                            acc[i][chh * 4 + 2], acc[i][chh * 4 + 3]);
        }
    }
}
__global__ void combine_bias(const float* __restrict__ eb2,
                             const float* __restrict__ Wke,
                             const float* __restrict__ Wve,
                             float* __restrict__ cb) {
    int x = blockIdx.x;
    int li = x & 7, kv = x >> 3;
    int l = li < 4 ? li : li + 1;
    int g = (li & 3) + 1;
    const float* Wp = (kv ? Wve : Wke) + (size_t)l * 16384;
    const float* eb = eb2 + g * 128;
    int cc = threadIdx.x;
    float a = 0.f;
    for (int j = 0; j < 128; j++) a = fmaf(eb[j], Wp[(size_t)j * 128 + cc], a);
    cb[l * 256 + kv * 128 + cc] = a;
}

// ============================ CSR construction =============================
__global__ void zero_i32(int* __restrict__ p, int n) {
    int i = blockIdx.x * 256 + threadIdx.x;
    if (i < n) p[i] = 0;
}
__global__ void hist_kernel(const int* __restrict__ dst, int E, int* __restrict__ deg) {
    int e = blockIdx.x * 256 + threadIdx.x;
    if (e < E) atomicAdd(&deg[dst[e]], 1);
}
__global__ __launch_bounds__(256) void exscan5(const int* __restrict__ deg0,
                                               int* __restrict__ off0,
                                               int* __restrict__ cursor0, int n) {
    int g = blockIdx.x;
    const int* deg = deg0 + (size_t)g * n;
    int* off = off0 + (size_t)g * (n + 1);
    int* cursor = cursor0 + (size_t)g * n;
    __shared__ int wsum[4];
    __shared__ int carry;
    int tid = threadIdx.x, lane = tid & 63, w = tid >> 6;
    if (tid == 0) carry = 0;
    __syncthreads();
    for (int base = 0; base < n; base += 256) {
        int v = (base + tid < n) ? deg[base + tid] : 0;
        int incl = v;
        for (int d = 1; d < 64; d <<= 1) {
            int t = __shfl_up(incl, d, 64);
            if (lane >= d) incl += t;
        }
        if (lane == 63) wsum[w] = incl;
        __syncthreads();
        int woff = 0;
        for (int i = 0; i < w; i++) woff += wsum[i];
        int total = wsum[0] + wsum[1] + wsum[2] + wsum[3];
        int excl = carry + woff + incl - v;
        if (base + tid < n) { off[base + tid] = excl; cursor[base + tid] = excl; }
        __syncthreads();
        if (tid == 0) carry += total;
        __syncthreads();
    }
    if (threadIdx.x == 0) off[n] = carry;
}
__global__ void scatter_kernel(const int* __restrict__ dst, int E,
                               int* __restrict__ cursor, int* __restrict__ eids) {
    int e = blockIdx.x * 256 + threadIdx.x;
    if (e < E) { int p = atomicAdd(&cursor[dst[e]], 1); eids[p] = e; }
}
__global__ void sort_edges(const int* __restrict__ eid, const int* __restrict__ srcArr,
                           const float* __restrict__ attr, int aw, int E,
                           int* __restrict__ esrc, float4* __restrict__ eattr) {
    int pos = blockIdx.x * 256 + threadIdx.x;
    if (pos >= E) return;
    int e = eid[pos];
    esrc[pos] = srcArr[e];
    if (attr) {
        float4 v;
        v.x = attr[(size_t)e * aw + 0];
        v.y = attr[(size_t)e * aw + 1];
        v.z = (aw > 2) ? attr[(size_t)e * aw + 2] : 0.f;
        v.w = (aw > 3) ? attr[(size_t)e * aw + 3] : 0.f;
        eattr[pos] = v;
    }
}

// ====== degree-sorted dst order: LDS-hierarchical counting sort, 33 bins ===
__global__ __launch_bounds__(256) void hist_deg2(const int* __restrict__ deg5, int n,
                                                 int* __restrict__ bh) {
    int g = blockIdx.y;
    const int* deg = deg5 + (size_t)g * n;
    __shared__ int lh[33];
    if (threadIdx.x < 33) lh[threadIdx.x] = 0;
    __syncthreads();
    int d = blockIdx.x * 256 + threadIdx.x;
    if (d < n) { int b = deg[d]; if (b > 32) b = 32; atomicAdd(&lh[b], 1); }
    __syncthreads();
    if (threadIdx.x < 33)
        bh[((size_t)g * NB_ + blockIdx.x) * 33 + threadIdx.x] = lh[threadIdx.x];
}
__global__ __launch_bounds__(64) void scan_bh(int* __restrict__ bh) {
    int g = blockIdx.x;
    int* p = bh + (size_t)g * NB_ * 33;
    __shared__ int tot[33], base[33];
    int bin = threadIdx.x;
    if (bin < 33) {
        int t = 0;
        for (int b = 0; b < NB_; b++) t += p[b * 33 + bin];
        tot[bin] = t;
    }
    __syncthreads();
    if (threadIdx.x == 0) {
        int acc = 0;
        for (int i = 0; i < 33; i++) { base[i] = acc; acc += tot[i]; }
    }
    __syncthreads();
    if (bin < 33) {
        int run = base[bin];
        for (int b = 0; b < NB_; b++) { int v = p[b * 33 + bin]; p[b * 33 + bin] = run; run += v; }
    }
}
__global__ __launch_bounds__(256) void scatter_ord2(const int* __restrict__ deg5, int n,
                                                    const int* __restrict__ bh,
                                                    int* __restrict__ dord5) {
    int g = blockIdx.y;
    const int* deg = deg5 + (size_t)g * n;
    int* dord = dord5 + (size_t)g * n;
    __shared__ int cur[33];
    if (threadIdx.x < 33)
        cur[threadIdx.x] = bh[((size_t)g * NB_ + blockIdx.x) * 33 + threadIdx.x];
    __syncthreads();
    int d = blockIdx.x * 256 + threadIdx.x;
    if (d < n) {
        int b = deg[d]; if (b > 32) b = 32;
        int p = atomicAdd(&cur[b], 1);
        dord[p] = d;
    }
}

// ====== prep_g: g[d][cp][h] = bf16( 0.25*sum_t Ck[cp][16h+t] q[d][16h+t] ) =
__global__ __launch_bounds__(256) void prep_g(const float* __restrict__ q,
                                              const float* __restrict__ cWl,
                                              const float* __restrict__ cbl,
                                              ushort* __restrict__ g,
                                              float* __restrict__ sb) {
    __shared__ float qs[8 * 132];
    int tid = threadIdx.x;
    int cp = tid & 127, hb = (tid >> 7) * 4;     // hb in {0,4}, wave-uniform
    float ck[64];
    {
        const float* csrc = cWl + (size_t)cp * 256 + hb * 16;
#pragma unroll
        for (int t4 = 0; t4 < 16; t4++) {
            float4 v = *(const float4*)(csrc + t4 * 4);
            ck[t4 * 4 + 0] = v.x; ck[t4 * 4 + 1] = v.y;
            ck[t4 * 4 + 2] = v.z; ck[t4 * 4 + 3] = v.w;
        }
    }
    int d0 = blockIdx.x * 8;
    {
        int dl = tid >> 5, col = (tid & 31) * 4;
        *(float4*)(qs + dl * 132 + col) = *(const float4*)(q + (size_t)(d0 + dl) * 128 + col);
    }
    __syncthreads();
#pragma unroll
    for (int dl = 0; dl < 8; dl++) {
        const float* qr = qs + dl * 132 + hb * 16;   // broadcast reads
        float a0 = 0.f, a1 = 0.f, a2 = 0.f, a3 = 0.f;
#pragma unroll
        for (int t = 0; t < 16; t++) {
            a0 = fmaf(ck[t],      qr[t],      a0);
            a1 = fmaf(ck[16 + t], qr[16 + t], a1);
            a2 = fmaf(ck[32 + t], qr[32 + t], a2);
            a3 = fmaf(ck[48 + t], qr[48 + t], a3);
        }
        ushort4 o = make_ushort4(f2bh(a0 * 0.25f), f2bh(a1 * 0.25f),
                                 f2bh(a2 * 0.25f), f2bh(a3 * 0.25f));
        *(ushort4*)(g + (size_t)(d0 + dl) * 1024 + cp * 8 + hb) = o;
    }
    if (tid < 64) {
        int dl = tid >> 3, h = tid & 7;
        const float* qr = qs + dl * 132 + h * 16;
        const float* cbr = cbl + h * 16;
        float a = 0.f;
#pragma unroll
        for (int t = 0; t < 16; t++) a = fmaf(cbr[t], qr[t], a);
        sb[(d0 + dl) * 8 + h] = a * 0.25f;
    }
}

// ===== fused attention (2-edge ILP, no-max softmax) + Cv epilogue ==========
static constexpr int HS_ = 136;   // padded h-stride: conflict-free hstage access
static constexpr int HW_ = 272;   // per-wave h region: 2 edges x128 + 16 bcast
__global__ __launch_bounds__(256) void attn_fact(const int* __restrict__ dord,
                                                 const int* __restrict__ off,
                                                 const int* __restrict__ esrc,
                                                 const float4* __restrict__ eattr,
                                                 const ushort* __restrict__ g,
                                                 const float* __restrict__ sb,
                                                 const float* __restrict__ eW1,
                                                 const float* __restrict__ eb1,
                                                 const float* __restrict__ q,
                                                 const ushort* __restrict__ kvp,
                                                 const float* __restrict__ cWl,
                                                 const float* __restrict__ cbl,
                                                 float* __restrict__ agg) {
    __shared__ float hw4[4 * HW_];
    __shared__ float hstage[4][8 * HS_];
    __shared__ float vstage[4][128];
    __shared__ float dens2[4][8];
    __shared__ float part[2][4][128];
    __shared__ int sD[4];
    int w = threadIdx.x >> 6, l = threadIdx.x & 63;
    int i = l & 15, hlo = l >> 4;
    float* hw = hw4 + w * HW_;   // [0..127] e0 h, [128..255] e1 h, [256..271] w bcast
    int d = dord[blockIdx.x * 4 + w];
    int beg = off[d], end = off[d + 1];
    float q0 = q[(size_t)d * 128 + l] * 0.25f;
    float q1 = q[(size_t)d * 128 + 64 + l] * 0.25f;
    float gA[8], gB[8];
#pragma unroll
    for (int j = 0; j < 8; j++) {
        gA[j] = bh2f(g[(size_t)d * 1024 + (j * 16 + i) * 8 + hlo]);
        gB[j] = bh2f(g[(size_t)d * 1024 + (j * 16 + i) * 8 + hlo + 4]);
    }
    float sbA = sb[d * 8 + hlo], sbB = sb[d * 8 + 4 + hlo];
    float w1a[4], w1b[4];
#pragma unroll
    for (int j = 0; j < 4; j++) { w1a[j] = eW1[j * 128 + l]; w1b[j] = eW1[j * 128 + 64 + l]; }
    float ebA = eb1[l], ebB = eb1[64 + l];
    float dnA = 0.f, dnB = 0.f;
    float accL[8] = {}, accH[8] = {};
    float va0 = 0.f, va1 = 0.f;
    // pair pipeline: slots 0,1 = current pair; reloaded with next pair
    float4 at0 = make_float4(0.f, 0.f, 0.f, 0.f), at1 = at0;
    ushort k00 = 0, k10 = 0, v00 = 0, v10 = 0;   // edge slot 0
    ushort k01 = 0, k11 = 0, v01 = 0, v11 = 0;   // edge slot 1
    auto LOADE = [&](int p, float4& at, ushort& ka, ushort& kb, ushort& va, ushort& vb) {
        int s = esrc[p]; at = eattr[p];
        const ushort* r = kvp + (size_t)s * 256;
        ka = r[l]; kb = r[64 + l];
        va = r[128 + l]; vb = r[192 + l];
    };
    if (beg < end) LOADE(beg, at0, k00, k10, v00, v10);
    if (beg + 1 < end) LOADE(beg + 1, at1, k01, k11, v01, v11);
    int pos = beg;
    while (pos + 1 < end) {
        float4 ca0 = at0, ca1 = at1;
        ushort ck00 = k00, ck10 = k10, cv00 = v00, cv10 = v10;
        ushort ck01 = k01, ck11 = k11, cv01 = v01, cv11 = v11;
        if (pos + 2 < end) LOADE(pos + 2, at0, k00, k10, v00, v10);
        if (pos + 3 < end) LOADE(pos + 3, at1, k01, k11, v01, v11);
        // h for both edges
        float h00 = fmaxf(ebA + ca0.x * w1a[0] + ca0.y * w1a[1] + ca0.z * w1a[2] + ca0.w * w1a[3], 0.f);
        float h10 = fmaxf(ebB + ca0.x * w1b[0] + ca0.y * w1b[1] + ca0.z * w1b[2] + ca0.w * w1b[3], 0.f);
        float h01 = fmaxf(ebA + ca1.x * w1a[0] + ca1.y * w1a[1] + ca1.z * w1a[2] + ca1.w * w1a[3], 0.f);
        float h11 = fmaxf(ebB + ca1.x * w1b[0] + ca1.y * w1b[1] + ca1.z * w1b[2] + ca1.w * w1b[3], 0.f);
        hw[l] = h00; hw[64 + l] = h10;
        hw[128 + l] = h01; hw[192 + l] = h11;
        __builtin_amdgcn_wave_barrier();
        float pA0 = q0 * bh2f(ck00), pB0 = q1 * bh2f(ck10);
        float pA1 = q0 * bh2f(ck01), pB1 = q1 * bh2f(ck11);
#pragma unroll
        for (int j = 0; j < 8; j++) {
            float hv0 = hw[j * 16 + i];
            float hv1 = hw[128 + j * 16 + i];
            pA0 = fmaf(hv0, gA[j], pA0);
            pB0 = fmaf(hv0, gB[j], pB0);
            pA1 = fmaf(hv1, gA[j], pA1);
            pB1 = fmaf(hv1, gB[j], pB1);
        }
#pragma unroll
        for (int msk = 1; msk < 16; msk <<= 1) {   // 4 chains interleave in DS pipe
            pA0 += __shfl_xor(pA0, msk, 64);
            pB0 += __shfl_xor(pB0, msk, 64);
            pA1 += __shfl_xor(pA1, msk, 64);
            pB1 += __shfl_xor(pB1, msk, 64);
        }
        float wA0 = __expf(pA0 + sbA), wA1 = __expf(pA1 + sbA);
        float wB0 = __expf(pB0 + sbB), wB1 = __expf(pB1 + sbB);
        dnA += wA0 + wA1; dnB += wB0 + wB1;
        va0 = fmaf(wA0, bh2f(cv00), fmaf(wA1, bh2f(cv01), va0));
        va1 = fmaf(wB0, bh2f(cv10), fmaf(wB1, bh2f(cv11), va1));
        if (i == 0) {
            hw[256 + hlo] = wA0; hw[260 + hlo] = wA1;
            hw[264 + hlo] = wB0; hw[268 + hlo] = wB1;
        }
        __builtin_amdgcn_wave_barrier();
        float4 WA0 = *(float4*)(hw + 256), WA1 = *(float4*)(hw + 260);
        float4 WB0 = *(float4*)(hw + 264), WB1 = *(float4*)(hw + 268);
#pragma unroll
        for (int j = 0; j < 4; j++) {
            float wa0 = ((const float*)&WA0)[j], wa1 = ((const float*)&WA1)[j];
            float wb0 = ((const float*)&WB0)[j], wb1 = ((const float*)&WB1)[j];
            accL[j]     = fmaf(wa0, h00, fmaf(wa1, h01, accL[j]));
            accH[j]     = fmaf(wa0, h10, fmaf(wa1, h11, accH[j]));
            accL[4 + j] = fmaf(wb0, h00, fmaf(wb1, h01, accL[4 + j]));
            accH[4 + j] = fmaf(wb0, h10, fmaf(wb1, h11, accH[4 + j]));
        }
        pos += 2;
    }
    if (pos < end) {   // odd tail: single edge in slot 0
        float h00 = fmaxf(ebA + at0.x * w1a[0] + at0.y * w1a[1] + at0.z * w1a[2] + at0.w * w1a[3], 0.f);
        float h10 = fmaxf(ebB + at0.x * w1b[0] + at0.y * w1b[1] + at0.z * w1b[2] + at0.w * w1b[3], 0.f);
        hw[l] = h00; hw[64 + l] = h10;
        __builtin_amdgcn_wave_barrier();
        float pA = q0 * bh2f(k00), pB = q1 * bh2f(k10);
#pragma unroll
        for (int j = 0; j < 8; j++) {
            float hv = hw[j * 16 + i];
            pA = fmaf(hv, gA[j], pA);
            pB = fmaf(hv, gB[j], pB);
        }
#pragma unroll
        for (int msk = 1; msk < 16; msk <<= 1) {
            pA += __shfl_xor(pA, msk, 64);
            pB += __shfl_xor(pB, msk, 64);
        }
        float wA = __expf(pA + sbA), wB = __expf(pB + sbB);
        dnA += wA; dnB += wB;
        va0 = fmaf(wA, bh2f(v00), va0);
        va1 = fmaf(wB, bh2f(v10), va1);
        if (i == 0) { hw[256 + hlo] = wA; hw[264 + hlo] = wB; }
        __builtin_amdgcn_wave_barrier();
        float4 WA = *(float4*)(hw + 256), WB = *(float4*)(hw + 264);
#pragma unroll
        for (int j = 0; j < 4; j++) {
            float wa = ((const float*)&WA)[j];
            float wb = ((const float*)&WB)[j];
            accL[j]     = fmaf(wa, h00, accL[j]);
            accH[j]     = fmaf(wa, h10, accH[j]);
            accL[4 + j] = fmaf(wb, h00, accL[4 + j]);
            accH[4 + j] = fmaf(wb, h10, accH[4 + j]);
        }
    }
    // stage per-dst state to LDS (padded h-stride HS_ = conflict-free)
#pragma unroll
    for (int h = 0; h < 8; h++) {
        hstage[w][h * HS_ + l]      = accL[h];
        hstage[w][h * HS_ + 64 + l] = accH[h];
    }
    vstage[w][l] = va0; vstage[w][64 + l] = va1;
    if (i == 0) { dens2[w][hlo] = dnA; dens2[w][4 + hlo] = dnB; }
    if (l == 0) sD[w] = d;
    __syncthreads();
    // epilogue pass 1: cp split across 2 halves; each Cv element loaded once,
    // used for all 4 dsts -> 64-deep load chain, 4 FMA per load.
    {
        int cc = threadIdx.x & 127, h2 = threadIdx.x >> 7;
        int hh = cc >> 4;
        int cp0 = h2 * 64;
        const float* cvp = cWl + 128 + cc + (size_t)cp0 * 256;
        const float* h0p = &hstage[0][hh * HS_ + cp0];
        const float* h1p = &hstage[1][hh * HS_ + cp0];
        const float* h2p = &hstage[2][hh * HS_ + cp0];
        const float* h3p = &hstage[3][hh * HS_ + cp0];
        float p0 = 0.f, p1 = 0.f, p2 = 0.f, p3 = 0.f;
#pragma unroll 8
        for (int cp = 0; cp < 64; cp++) {
            float cv = cvp[(size_t)cp * 256];
            p0 = fmaf(h0p[cp], cv, p0);
            p1 = fmaf(h1p[cp], cv, p1);
            p2 = fmaf(h2p[cp], cv, p2);
            p3 = fmaf(h3p[cp], cv, p3);
        }
        part[h2][0][cc] = p0; part[h2][1][cc] = p1;
        part[h2][2][cc] = p2; part[h2][3][cc] = p3;
    }
    __syncthreads();
    // epilogue pass 2: combine halves, normalize, write 2 dsts per thread
    {
        int cc = threadIdx.x & 127, h2 = threadIdx.x >> 7;
        int hh = cc >> 4;
        float cvb = cbl[128 + cc];
#pragma unroll
        for (int t = 0; t < 2; t++) {
            int ds = h2 * 2 + t;
            float dn = dens2[ds][hh];
            float inv = 1.f / (dn + 1e-9f);
            float cf = dn * inv;
            float a = part[0][ds][cc] + part[1][ds][cc];
            agg[(size_t)sD[ds] * 128 + cc] = (vstage[ds][cc] + a) * inv + cvb * cf;
        }
    }
}

// ===== plain fused attention (2-edge ILP, no-max softmax) ==================
__global__ __launch_bounds__(256) void attn_plain(const int* __restrict__ dord,
                                                  const int* __restrict__ off,
                                                  const int* __restrict__ esrc,
                                                  const float* __restrict__ q,
                                                  const ushort* __restrict__ kvp,
                                                  float* __restrict__ agg) {
    int lane = threadIdx.x & 63;
    int d = dord[blockIdx.x * 4 + (threadIdx.x >> 6)];
    int beg = off[d], end = off[d + 1];
    float q0 = q[(size_t)d * 128 + lane] * 0.25f;
    float q1 = q[(size_t)d * 128 + 64 + lane] * 0.25f;
    float den0 = 0.f, den1 = 0.f, acc0 = 0.f, acc1 = 0.f;
    ushort k00 = 0, k10 = 0, v00 = 0, v10 = 0;
    ushort k01 = 0, k11 = 0, v01 = 0, v11 = 0;
    auto LOADE = [&](int p, ushort& ka, ushort& kb, ushort& va, ushort& vb) {
        int s = esrc[p];
        const ushort* r = kvp + (size_t)s * 256;
        ka = r[lane]; kb = r[64 + lane];
        va = r[128 + lane]; vb = r[192 + lane];
    };
    if (beg < end) LOADE(beg, k00, k10, v00, v10);
    if (beg + 1 < end) LOADE(beg + 1, k01, k11, v01, v11);
    int pos = beg;
    while (pos + 1 < end) {
        ushort ck00 = k00, ck10 = k10, cv00 = v00, cv10 = v10;
        ushort ck01 = k01, ck11 = k11, cv01 = v01, cv11 = v11;
        if (pos + 2 < end) LOADE(pos + 2, k00, k10, v00, v10);
        if (pos + 3 < end) LOADE(pos + 3, k01, k11, v01, v11);
        float p00 = q0 * bh2f(ck00), p10 = q1 * bh2f(ck10);
        float p01 = q0 * bh2f(ck01), p11 = q1 * bh2f(ck11);
#pragma unroll
        for (int msk = 1; msk < 16; msk <<= 1) {
            p00 += __shfl_xor(p00, msk, 64);
            p10 += __shfl_xor(p10, msk, 64);
            p01 += __shfl_xor(p01, msk, 64);
            p11 += __shfl_xor(p11, msk, 64);
        }
        float w00 = __expf(p00), w01 = __expf(p01);
        float w10 = __expf(p10), w11 = __expf(p11);
        den0 += w00 + w01; den1 += w10 + w11;
        acc0 = fmaf(w00, bh2f(cv00), fmaf(w01, bh2f(cv01), acc0));
        acc1 = fmaf(w10, bh2f(cv10), fmaf(w11, bh2f(cv11), acc1));
        pos += 2;
    }
    if (pos < end) {
        float p0 = q0 * bh2f(k00), p1 = q1 * bh2f(k10);
#pragma unroll
        for (int msk = 1; msk < 16; msk <<= 1) {
            p0 += __shfl_xor(p0, msk, 64);
            p1 += __shfl_xor(p1, msk, 64);
        }
        float w0 = __expf(p0), w1 = __expf(p1);
        den0 += w0; den1 += w1;
        acc0 = fmaf(w0, bh2f(v00), acc0);
        acc1 = fmaf(w1, bh2f(v10), acc1);
    }
    agg[(size_t)d * 128 + lane]      = acc0 / (den0 + 1e-9f);
    agg[(size_t)d * 128 + 64 + lane] = acc1 / (den1 + 1e-9f);
}

// ======================= small glue kernels ================================
__global__ void mode_init(float* __restrict__ m, const float* __restrict__ mt) {
    int idx = blockIdx.x * 256 + threadIdx.x;
    if (idx >= M_ * H_) return;
    int node = idx >> 7, c = idx & 127;
    m[idx] = mt[(node % K_) * H_ + c];
}
__global__ void extract_last(const float* __restrict__ m, float* __restrict__ out) {
    int idx = blockIdx.x * 256 + threadIdx.x;
    if (idx >= AK_ * H_) return;
    int row = idx >> 7, c = idx & 127;
    int a = row / K_, k = row - a * K_;
    int node = (a * T_ + (T_ - 1)) * K_ + k;
    out[idx] = m[(size_t)node * H_ + c];
}
__global__ void add_anchor(float* __restrict__ m, const float* __restrict__ anchor) {
    int idx = blockIdx.x * 256 + threadIdx.x;
    if (idx >= M_ * H_) return;
    int node = idx >> 7, c = idx & 127;
    int a = node / (T_ * K_), k = node % K_;
    m[idx] += anchor[(size_t)(a * K_ + k) * H_ + c];
}

// ============================ host launch ==================================
extern "C" void kernel_launch(void* const* d_in, const int* in_sizes, int n_in,
                              void* d_out, int out_size, void* d_ws, size_t ws_size,
                              hipStream_t stream) {
    const float* a_input     = (const float*)d_in[0];
    const float* l_embs      = (const float*)d_in[1];
    const float* mode_tokens = (const float*)d_in[2];
    const float* emb_W1 = (const float*)d_in[3];
    const float* emb_b1 = (const float*)d_in[4];
    const float* emb_W2 = (const float*)d_in[5];
    const float* emb_b2 = (const float*)d_in[6];
    const float* ga_Wq  = (const float*)d_in[7];
    const float* ga_Wk  = (const float*)d_in[8];
    const float* ga_Wv  = (const float*)d_in[9];
    const float* ga_Wo  = (const float*)d_in[10];
    const float* ga_Wke = (const float*)d_in[11];
    const float* ga_Wve = (const float*)d_in[12];
    const float* ga_g1  = (const float*)d_in[13];
    const float* ga_b1  = (const float*)d_in[14];
    const float* ga_g2  = (const float*)d_in[15];
    const float* ga_b2  = (const float*)d_in[16];
    const float* ga_fW1 = (const float*)d_in[17];
    const float* ga_fb1 = (const float*)d_in[18];
    const float* ga_fW2 = (const float*)d_in[19];
    const float* ga_fb2 = (const float*)d_in[20];
    const float* tp_W1 = (const float*)d_in[21];
    const float* tp_b1 = (const float*)d_in[22];
    const float* tp_W2 = (const float*)d_in[23];
    const float* tp_b2 = (const float*)d_in[24];
    const float* pa_W1 = (const float*)d_in[25];
    const float* pa_b1 = (const float*)d_in[26];
    const float* pa_W2 = (const float*)d_in[27];
    const float* pa_b2 = (const float*)d_in[28];
    const float* tr_W1 = (const float*)d_in[29];
    const float* tr_b1 = (const float*)d_in[30];
    const float* tr_W2 = (const float*)d_in[31];
    const float* tr_b2 = (const float*)d_in[32];
    const float* attrs[4] = { (const float*)d_in[33], (const float*)d_in[34],
                              (const float*)d_in[35], (const float*)d_in[36] };
    const int* eis[5] = { (const int*)d_in[37], (const int*)d_in[38], (const int*)d_in[39],
                          (const int*)d_in[40], (const int*)d_in[41] };
    int Es[5];
    int Emax = 0;
    for (int i = 0; i < 5; i++) { Es[i] = in_sizes[37 + i] / 2; if (Es[i] > Emax) Emax = Es[i]; }

    size_t off = 0;
    auto alloc = [&](size_t nbytes) -> char* {
        char* p = (char*)d_ws + off;
        off += ((nbytes + 255) / 256) * 256;
        return p;
    };
    float* cW     = (float*)alloc((size_t)NL_ * 128 * 256 * 4);
    float* cb     = (float*)alloc((size_t)NL_ * 256 * 4);
    ushort* wbh   = (ushort*)alloc((size_t)NL_ * WLAY * 2);
    ushort* wbl   = (ushort*)alloc((size_t)NL_ * WLAY * 2);
    float* a_embs = (float*)alloc((size_t)AT_ * H_ * 4);
    float* m      = (float*)alloc((size_t)M_ * H_ * 4);
    float* q      = (float*)alloc((size_t)M_ * H_ * 4);
    ushort* kvb   = (ushort*)alloc((size_t)M_ * 256 * 2);    // bf16 k|v fused
    float* agg    = (float*)alloc((size_t)M_ * H_ * 4);
    float* big    = (float*)alloc((size_t)M_ * FF_ * 4);     // FFN hidden
    ushort* gbuf  = (ushort*)alloc((size_t)M_ * 1024 * 2);   // bf16 g [d][cp][h]
    float* sb     = (float*)alloc((size_t)M_ * 8 * 4);
    float* muM    = (float*)alloc((size_t)M_ * 4);
    float* rsM    = (float*)alloc((size_t)M_ * 4);
    float* muA    = (float*)alloc((size_t)AT_ * 4);
    float* rsA    = (float*)alloc((size_t)AT_ * 4);
    float* muL    = (float*)alloc((size_t)L_ * 4);
    float* rsL    = (float*)alloc((size_t)L_ * 4);
    int* csr_off  = (int*)alloc((size_t)5 * (M_ + 1) * 4);
    int* csr_eid  = (int*)alloc((size_t)5 * Emax * 4);
    int* esrc     = (int*)alloc((size_t)5 * Emax * 4);
    float4* eattr = (float4*)alloc((size_t)4 * Emax * 16);
    int* deg5     = (int*)alloc((size_t)5 * M_ * 4);
    int* cursor5  = (int*)alloc((size_t)5 * M_ * 4);
    int* dord5    = (int*)alloc((size_t)5 * M_ * 4);
    int* bh5      = (int*)alloc((size_t)5 * NB_ * 33 * 4);
    float* mlast  = (float*)alloc((size_t)AK_ * H_ * 4);
    float* hbuf   = (float*)alloc((size_t)AK_ * H_ * 4);
    float* anchor = (float*)alloc((size_t)AK_ * H_ * 4);
    (void)ws_size; (void)n_in;

    float* outp = (float*)d_out;

    // ---- CSR + sorted src/attr + degree-sorted dst order for 5 graphs ----
    zero_i32<<<(5 * M_ + 255) / 256, 256, 0, stream>>>(deg5, 5 * M_);
    for (int gI = 0; gI < 5; gI++)
        hist_kernel<<<(Es[gI] + 255) / 256, 256, 0, stream>>>(eis[gI] + Es[gI], Es[gI], deg5 + (size_t)gI * M_);
    exscan5<<<5, 256, 0, stream>>>(deg5, csr_off, cursor5, M_);
    for (int gI = 0; gI < 5; gI++)
        scatter_kernel<<<(Es[gI] + 255) / 256, 256, 0, stream>>>(eis[gI] + Es[gI], Es[gI],
            cursor5 + (size_t)gI * M_, csr_eid + (size_t)gI * Emax);
    for (int gI = 0; gI < 5; gI++) {
        int aw = (gI == 0 || gI == 2) ? 4 : (gI == 4 ? 0 : 3);
        sort_edges<<<(Es[gI] + 255) / 256, 256, 0, stream>>>(
            csr_eid + (size_t)gI * Emax, eis[gI], (gI < 4) ? attrs[gI] : nullptr, aw, Es[gI],
            esrc + (size_t)gI * Emax, eattr + (size_t)gI * Emax);
    }
    hist_deg2<<<dim3(NB_, 5), 256, 0, stream>>>(deg5, M_, bh5);
    scan_bh<<<5, 64, 0, stream>>>(bh5);
    scatter_ord2<<<dim3(NB_, 5), 256, 0, stream>>>(deg5, M_, bh5, dord5);

    // ---- weight prep ----
    prep_w<<<dim3(192, 10), 256, 0, stream>>>(ga_Wq, ga_Wk, ga_Wv, ga_Wo, ga_fW1, ga_fW2, wbh, wbl);
    combine_fast<<<16, 256, 0, stream>>>(emb_W2, ga_Wke, ga_Wve, cW);
    combine_bias<<<16, 128, 0, stream>>>(emb_b2, ga_Wke, ga_Wve, cb);

    // ---- embeddings / init ----
    small_gemm<1, false><<<(AT_ * H_ + 255) / 256, 256, 0, stream>>>(a_input, emb_W1, emb_b1, nullptr, big, AT_, 5, H_);
    small_gemm<0, false><<<(AT_ * H_ + 255) / 256, 256, 0, stream>>>(big, emb_W2, emb_b2, nullptr, a_embs, AT_, H_, H_);
    mode_init<<<(M_ * H_ + 255) / 256, 256, 0, stream>>>(m, mode_tokens);
    ln_stats<<<M_ / 4, 256, 0, stream>>>(m, muM, rsM, M_);
    ln_stats<<<AT_ / 4, 256, 0, stream>>>(a_embs, muA, rsA, AT_);
    ln_stats<<<L_ / 4, 256, 0, stream>>>(l_embs, muL, rsL, L_);

    struct Cfg { const float* srcX; const float* muS; const float* rsS; int n_src; int gi; bool hasE; };
    Cfg cfgs[10] = {
        { a_embs, muA, rsA, AT_, 0, true }, { l_embs, muL, rsL, L_, 1, true },
        { nullptr, nullptr, nullptr, M_, 2, true }, { nullptr, nullptr, nullptr, M_, 3, true },
        { nullptr, nullptr, nullptr, M_, 4, false },
        { a_embs, muA, rsA, AT_, 0, true }, { l_embs, muL, rsL, L_, 1, true },
        { nullptr, nullptr, nullptr, M_, 2, true }, { nullptr, nullptr, nullptr, M_, 3, true },
        { nullptr, nullptr, nullptr, M_, 4, false },
    };

    for (int l = 0; l < 10; l++) {
        const Cfg& cf = cfgs[l];
        const int* offg = csr_off + cf.gi * (M_ + 1);
        const int* esrcg = esrc + (size_t)cf.gi * Emax;
        const float4* eattrg = eattr + (size_t)cf.gi * Emax;
        const int* dordg = dord5 + (size_t)cf.gi * M_;
        const float* g1 = ga_g1 + l * H_; const float* b1 = ga_b1 + l * H_;
        size_t wb = (size_t)l * WLAY;

        // muM/rsM currently hold LN1 stats of m (from prev FFN2 STATS / init)
        if (cf.srcX) {
            mgemm<0, false, 0, true, false><<<dim3(M_ / 128, 1), 256, 0, stream>>>(
                m, wbh + wb, wbl + wb, nullptr, nullptr, q, nullptr,
                muM, rsM, g1, b1, nullptr, nullptr, M_, 128, 128);
            mgemm<0, false, 1, true, false><<<dim3(cf.n_src / 128, 2), 256, 0, stream>>>(
                cf.srcX, wbh + wb + 16384, wbl + wb + 16384, nullptr, nullptr, nullptr, kvb,
                cf.muS, cf.rsS, g1, b1, nullptr, nullptr, cf.n_src, 128, 256);
        } else {
            mgemm<0, false, 2, true, false><<<dim3(M_ / 128, 3), 256, 0, stream>>>(
                m, wbh + wb, wbl + wb, nullptr, nullptr, q, kvb,
                muM, rsM, g1, b1, nullptr, nullptr, M_, 128, 384);
        }

        if (cf.hasE) {
            int gg = (l < 5) ? l + 1 : l - 4;
            const float* eW1g = emb_W1 + (size_t)gg * 5 * H_;
            const float* eb1g = emb_b1 + (size_t)gg * H_;
            prep_g<<<M_ / 8, 256, 0, stream>>>(q, cW + (size_t)l * 32768, cb + l * 256, gbuf, sb);
            attn_fact<<<M_ / 4, 256, 0, stream>>>(dordg, offg, esrcg, eattrg, gbuf, sb, eW1g, eb1g,
                                                  q, kvb, cW + (size_t)l * 32768, cb + l * 256, agg);
        } else {
            attn_plain<<<M_ / 4, 256, 0, stream>>>(dordg, offg, esrcg, q, kvb, agg);
        }

        // m += agg @ Wo   (+ LN2 stats fused)
        mgemm<0, true, 0, false, true><<<dim3(M_ / 128, 1), 256, 0, stream>>>(
            agg, wbh + wb + 49152, wbl + wb + 49152, nullptr, m, m, nullptr,
            nullptr, nullptr, nullptr, nullptr, muM, rsM, M_, 128, 128);
        // FFN with fused LN2
        mgemm<1, false, 0, true, false><<<dim3(M_ / 128, 4), 256, 0, stream>>>(
            m, wbh + wb + 65536, wbl + wb + 65536, ga_fb1 + l * FF_, nullptr, big, nullptr,
            muM, rsM, ga_g2 + l * H_, ga_b2 + l * H_, nullptr, nullptr, M_, 128, 512);
        // FFN2 (+ next-layer LN1 stats fused)
        mgemm<0, true, 0, false, true><<<dim3(M_ / 128, 1), 256, 0, stream>>>(
            big, wbh + wb + 131072, wbl + wb + 131072, ga_fb2 + l * H_, m, m, nullptr,
            nullptr, nullptr, nullptr, nullptr, muM, rsM, M_, 512, 128);

        if (l == 4) {
            extract_last<<<(AK_ * H_ + 255) / 256, 256, 0, stream>>>(m, mlast);
            small_gemm<1, false><<<(AK_ * H_ + 255) / 256, 256, 0, stream>>>(mlast, tp_W1, tp_b1, nullptr, hbuf, AK_, H_, H_);
            small_gemm<0, false><<<(AK_ * P2F + 255) / 256, 256, 0, stream>>>(hbuf, tp_W2, tp_b2, nullptr, outp, AK_, H_, P2F);
            small_gemm<1, false><<<(AK_ * H_ + 255) / 256, 256, 0, stream>>>(outp, pa_W1, pa_b1, nullptr, hbuf, AK_, P2F, H_);
            small_gemm<0, false><<<(AK_ * H_ + 255) / 256, 256, 0, stream>>>(hbuf, pa_W2, pa_b2, nullptr, anchor, AK_, H_, H_);
            add_anchor<<<(M_ * H_ + 255) / 256, 256, 0, stream>>>(m, anchor);
            ln_stats<<<M_ / 4, 256, 0, stream>>>(m, muM, rsM, M_);   // m changed
        }
    }

    extract_last<<<(AK_ * H_ + 255) / 256, 256, 0, stream>>>(m, mlast);
    small_gemm<1, false><<<(AK_ * H_ + 255) / 256, 256, 0, stream>>>(mlast, tr_W1, tr_b1, nullptr, hbuf, AK_, H_, H_);
    small_gemm<0, true><<<(AK_ * P2F + 255) / 256, 256, 0, stream>>>(hbuf, tr_W2, tr_b2, outp, outp + AK_ * P2F, AK_, H_, P2F);
}

// Round 16
// 2377.893 us; speedup vs baseline: 1.0152x; 1.0152x over previous
//
#include <hip/hip_runtime.h>
#include <hip/hip_bf16.h>
#include <math.h>

#define DEV __device__ __forceinline__

typedef __attribute__((ext_vector_type(4))) float floatx4;
typedef __attribute__((ext_vector_type(8))) __bf16 bf16x8;

static constexpr int A_ = 64, T_ = 50, K_ = 6, H_ = 128, NH_ = 8, F_ = 60, L_ = 512;
static constexpr int M_  = A_ * T_ * K_;   // 19200 mode nodes
static constexpr int AT_ = A_ * T_;        // 3200
static constexpr int FF_ = 4 * H_;         // 512
static constexpr int NL_ = 10;
static constexpr int P2F = 2 * F_;         // 120
static constexpr int AK_ = A_ * K_;        // 384
static constexpr size_t WLAY = 196608;     // per-layer transposed-weight elems
static constexpr int NB_ = (M_ + 255) / 256;  // 75 blocks for M-sized grids

// ---- bf16 split helpers ----
DEV ushort f2bh(float f) {                 // RNE float->bf16 bits
    unsigned u = __float_as_uint(f);
    unsigned r = u + 0x7FFFu + ((u >> 16) & 1u);
    return (ushort)(r >> 16);
}
DEV float bh2f(ushort h) { return __uint_as_float(((unsigned)h) << 16); }

// ============ ln_stats: per-row mean / rsqrt(var+eps), one wave per row ====
__global__ __launch_bounds__(256) void ln_stats(const float* __restrict__ x,
                                                float* __restrict__ mu,
                                                float* __restrict__ rs, int n) {
    int row = blockIdx.x * 4 + (threadIdx.x >> 6);
    int lane = threadIdx.x & 63;
    if (row >= n) return;
    const float* xr = x + (size_t)row * H_;
    float v0 = xr[lane], v1 = xr[lane + 64];
    float s = v0 + v1;
    for (int m = 32; m >= 1; m >>= 1) s += __shfl_xor(s, m, 64);
    float m_ = s * (1.f / 128.f);
    float d0 = v0 - m_, d1 = v1 - m_;
    float vs = d0 * d0 + d1 * d1;
    for (int m = 32; m >= 1; m >>= 1) vs += __shfl_xor(vs, m, 64);
    if (lane == 0) {
        mu[row] = m_;
        rs[row] = rsqrtf(vs * (1.f / 128.f) + 1e-5f);
    }
}

// ====== split-bf16 MFMA GEMM: Y = act(LN?(X) @ W + bias) (+res) ===========
// OMODE: 0 = f32 out (+RES), 1 = bf16 out, 2 = mixed (col-block 0 -> f32 Y
// stride 128; col-blocks 1,2 -> bf16 Yb stride 256). LNX: apply layernorm
// during staging (Kd==128). STATS: emit per-row mu/rs of the final output
// (requires OMODE 0, C==128, single col-block).
template <int ACT, bool RES, int OMODE, bool LNX, bool STATS>
__global__ __launch_bounds__(256) void mgemm(const float* __restrict__ X,
                                             const ushort* __restrict__ Wh,
                                             const ushort* __restrict__ Wl,
                                             const float* __restrict__ bias,
                                             const float* __restrict__ res,
                                             float* __restrict__ Y,
                                             ushort* __restrict__ Yb,
                                             const float* __restrict__ muv,
                                             const float* __restrict__ rsv,
                                             const float* __restrict__ lng,
                                             const float* __restrict__ lnb,
                                             float* __restrict__ muo,
                                             float* __restrict__ rso,
                                             int n, int Kd, int C) {
    __shared__ ushort lds[4 * 8192];           // Xh,Xl,Wsh,Wsl: [128][64] each
    ushort* Xh  = lds;
    ushort* Xl  = lds + 8192;
    ushort* Wsh = lds + 16384;
    ushort* Wsl = lds + 24576;
    int row0 = blockIdx.x * 128, col0 = blockIdx.y * 128;
    int tid = threadIdx.x;
    int lane = tid & 63, wid = tid >> 6;
    int rbase = (wid >> 1) * 64, cbase = (wid & 1) * 64;
    int lrow = lane & 15, lk = lane >> 4;
    floatx4 acc[4][4];
#pragma unroll
    for (int a = 0; a < 4; a++)
#pragma unroll
        for (int b2 = 0; b2 < 4; b2++) acc[a][b2] = floatx4{0.f, 0.f, 0.f, 0.f};

    for (int k0 = 0; k0 < Kd; k0 += 64) {
        float4 g4, b4;
        if (LNX) {
            int kcol = k0 + (tid & 15) * 4;
            g4 = *(const float4*)(lng + kcol);
            b4 = *(const float4*)(lnb + kcol);
        }
#pragma unroll
        for (int i = 0; i < 8; i++) {
            int idx = tid + i * 256;
            int r = idx >> 4, kc = idx & 15;
            float4 v = *(const float4*)(X + (size_t)(row0 + r) * Kd + k0 + kc * 4);
            if (LNX) {
                float mur = muv[row0 + r];
                float rsr = rsv[row0 + r];
                v.x = (v.x - mur) * rsr * g4.x + b4.x;
                v.y = (v.y - mur) * rsr * g4.y + b4.y;
                v.z = (v.z - mur) * rsr * g4.z + b4.z;
                v.w = (v.w - mur) * rsr * g4.w + b4.w;
            }
            ushort h0 = f2bh(v.x), h1 = f2bh(v.y), h2 = f2bh(v.z), h3 = f2bh(v.w);
            ushort l0 = f2bh(v.x - bh2f(h0)), l1 = f2bh(v.y - bh2f(h1)),
                   l2 = f2bh(v.z - bh2f(h2)), l3 = f2bh(v.w - bh2f(h3));
            int base = (r << 6) + (((kc >> 1) ^ (r & 7)) << 3) + ((kc & 1) << 2);
            *(ushort4*)(Xh + base) = make_ushort4(h0, h1, h2, h3);
            *(ushort4*)(Xl + base) = make_ushort4(l0, l1, l2, l3);
        }
#pragma unroll
        for (int i = 0; i < 4; i++) {
            int idx = tid + i * 256;
            int c = idx >> 3, ch = idx & 7;
            int base = (c << 6) + ((ch ^ (c & 7)) << 3);
            size_t go = (size_t)(col0 + c) * Kd + k0 + ch * 8;
            *(float4*)(Wsh + base) = *(const float4*)(Wh + go);
            *(float4*)(Wsl + base) = *(const float4*)(Wl + go);
        }
        __syncthreads();
#pragma unroll
        for (int kk = 0; kk < 2; kk++) {
            int ch = kk * 4 + lk;
            bf16x8 xh[4], xl[4], wh[4], wl[4];
#pragma unroll
            for (int s = 0; s < 4; s++) {
                int r = rbase + s * 16 + lrow;
                int xoff = (r << 6) + ((ch ^ (r & 7)) << 3);
                xh[s] = *(const bf16x8*)(Xh + xoff);
                xl[s] = *(const bf16x8*)(Xl + xoff);
                int c = cbase + s * 16 + lrow;
                int woff = (c << 6) + ((ch ^ (c & 7)) << 3);
                wh[s] = *(const bf16x8*)(Wsh + woff);
                wl[s] = *(const bf16x8*)(Wsl + woff);
            }
#pragma unroll
            for (int sr = 0; sr < 4; sr++)
#pragma unroll
                for (int sc = 0; sc < 4; sc++) {
                    acc[sr][sc] = __builtin_amdgcn_mfma_f32_16x16x32_bf16(wh[sc], xh[sr], acc[sr][sc], 0, 0, 0);
                    acc[sr][sc] = __builtin_amdgcn_mfma_f32_16x16x32_bf16(wl[sc], xh[sr], acc[sr][sc], 0, 0, 0);
                    acc[sr][sc] = __builtin_amdgcn_mfma_f32_16x16x32_bf16(wh[sc], xl[sr], acc[sr][sc], 0, 0, 0);
                }
        }
        __syncthreads();
    }
    float rowsum[4] = {}, rowsq[4] = {};
#pragma unroll
    for (int sr = 0; sr < 4; sr++) {
        int row = row0 + rbase + sr * 16 + lrow;
#pragma unroll
        for (int sc = 0; sc < 4; sc++) {
            int col = col0 + cbase + sc * 16 + lk * 4;
            float4 v = make_float4(acc[sr][sc][0], acc[sr][sc][1],
                                   acc[sr][sc][2], acc[sr][sc][3]);
            if (bias) { float4 bv = *(const float4*)(bias + col);
                        v.x += bv.x; v.y += bv.y; v.z += bv.z; v.w += bv.w; }
            if (ACT == 1) { v.x = fmaxf(v.x, 0.f); v.y = fmaxf(v.y, 0.f);
                            v.z = fmaxf(v.z, 0.f); v.w = fmaxf(v.w, 0.f); }
            if (OMODE == 0) {
                size_t o = (size_t)row * C + col;
                if (RES) { float4 rv = *(const float4*)(res + o);
                           v.x += rv.x; v.y += rv.y; v.z += rv.z; v.w += rv.w; }
                if (STATS) {
                    rowsum[sr] += v.x + v.y + v.z + v.w;
                    rowsq[sr]  += v.x * v.x + v.y * v.y + v.z * v.z + v.w * v.w;
                }
                *(float4*)(Y + o) = v;
            } else if (OMODE == 1) {
                size_t o = (size_t)row * C + col;
                *(ushort4*)(Yb + o) = make_ushort4(f2bh(v.x), f2bh(v.y), f2bh(v.z), f2bh(v.w));
            } else {
                if (col0 == 0) {
                    *(float4*)(Y + (size_t)row * 128 + col) = v;
                } else {
                    *(ushort4*)(Yb + (size_t)row * 256 + (col - 128)) =
                        make_ushort4(f2bh(v.x), f2bh(v.y), f2bh(v.z), f2bh(v.w));
                }
            }
        }
    }
    if (STATS) {
        float* sums = (float*)lds;            // [128][8]
        float* sqs  = ((float*)lds) + 1024;   // [128][8]
        int slot = (wid & 1) * 4 + lk;
#pragma unroll
        for (int sr = 0; sr < 4; sr++) {
            int rl = rbase + sr * 16 + lrow;
            sums[rl * 8 + slot] = rowsum[sr];
            sqs[rl * 8 + slot]  = rowsq[sr];
        }
        __syncthreads();
        if (tid < 128) {
            float s = 0.f, sq = 0.f;
#pragma unroll
            for (int t = 0; t < 8; t++) { s += sums[tid * 8 + t]; sq += sqs[tid * 8 + t]; }
            float mu = s * (1.f / 128.f);
            float var = sq * (1.f / 128.f) - mu * mu;
            muo[row0 + tid] = mu;
            rso[row0 + tid] = rsqrtf(var + 1e-5f);
        }
    }
}

// ==== prep_w: transpose+split all per-layer GEMM weights to bf16 [C][K] ====
__global__ __launch_bounds__(256) void prep_w(const float* __restrict__ Wq,
                                              const float* __restrict__ Wk,
                                              const float* __restrict__ Wv,
                                              const float* __restrict__ Wo,
                                              const float* __restrict__ fW1,
                                              const float* __restrict__ fW2,
                                              ushort* __restrict__ oh,
                                              ushort* __restrict__ ol) {
    int l = blockIdx.y, t = blockIdx.x;
    const float* src; int K, C, tiles_c; size_t obase;
    if (t < 64) {
        int mi = t >> 4; t &= 15;
        src = (mi == 0 ? Wq : mi == 1 ? Wk : mi == 2 ? Wv : Wo) + (size_t)l * 16384;
        K = 128; C = 128; tiles_c = 4; obase = (size_t)l * WLAY + (size_t)mi * 16384;
    } else if (t < 128) {
        t -= 64; src = fW1 + (size_t)l * 65536;
        K = 128; C = 512; tiles_c = 16; obase = (size_t)l * WLAY + 65536;
    } else {
        t -= 128; src = fW2 + (size_t)l * 65536;
        K = 512; C = 128; tiles_c = 4; obase = (size_t)l * WLAY + 131072;
    }
    int tc = t % tiles_c, tk = t / tiles_c;
    __shared__ float tile[32][33];
    int tx = threadIdx.x & 31, ty = threadIdx.x >> 5;
#pragma unroll
    for (int i = 0; i < 4; i++) {
        int k = tk * 32 + ty + i * 8;
        tile[ty + i * 8][tx] = src[(size_t)k * C + tc * 32 + tx];
    }
    __syncthreads();
#pragma unroll
    for (int i = 0; i < 4; i++) {
        int c = tc * 32 + ty + i * 8;
        float v = tile[tx][ty + i * 8];
        ushort h = f2bh(v);
        ushort lo = f2bh(v - bh2f(h));
        size_t o = obase + (size_t)c * K + tk * 32 + tx;
        oh[o] = h; ol[o] = lo;
    }
}

// ============== naive GEMM for small/ragged shapes =========================
template <int ACT, bool RES>
__global__ void small_gemm(const float* __restrict__ X, const float* __restrict__ W,
                           const float* __restrict__ bias, const float* __restrict__ res,
                           float* __restrict__ Y, int n, int Kd, int C) {
    int idx = blockIdx.x * 256 + threadIdx.x;
    if (idx >= n * C) return;
    int row = idx / C, c = idx - row * C;
    float a = bias ? bias[c] : 0.f;
    const float* xr = X + (size_t)row * Kd;
    for (int k = 0; k < Kd; k++) a = fmaf(xr[k], W[(size_t)k * C + c], a);
    if (ACT == 1) a = fmaxf(a, 0.f);
    if (RES) a += res[idx];
    Y[idx] = a;
}

// ==== combined weights cW[l][k][c256]: tiled f32 GEMM, 16 blocks ===========
__global__ __launch_bounds__(256) void combine_fast(const float* __restrict__ eW2,
                                                    const float* __restrict__ Wke,
                                                    const float* __restrict__ Wve,
                                                    float* __restrict__ cW) {
    __shared__ float Xs[128 * 36];
    __shared__ float Ws[32 * 128];
    int x = blockIdx.x;
    int li = x & 7, kv = x >> 3;
    int l = li < 4 ? li : li + 1;
    int g = (li & 3) + 1;
    const float* E2 = eW2 + (size_t)g * 16384;
    const float* Wp = (kv ? Wve : Wke) + (size_t)l * 16384;
    float* out = cW + (size_t)l * 32768 + kv * 128;
    int tid = threadIdx.x;
    int tc = tid & 15, tr = tid >> 4;
    int cA = tc * 4, rA = tr * 4;
    float acc[8][8] = {};
    for (int j0 = 0; j0 < 128; j0 += 32) {
#pragma unroll
        for (int i = 0; i < 4; i++) {
            int idx = tid + i * 256;
            int r = idx >> 3, jc = idx & 7;
            *(float4*)(Xs + r * 36 + jc * 4) =
                *(const float4*)(E2 + (size_t)r * 128 + j0 + jc * 4);
        }
#pragma unroll
        for (int i = 0; i < 4; i++) {
            int idx = tid + i * 256;
            int cc = idx & 31, jj = idx >> 5;
            *(float4*)(Ws + jj * 128 + cc * 4) =
                *(const float4*)(Wp + (size_t)(j0 + jj) * 128 + cc * 4);
        }
        __syncthreads();
#pragma unroll 8
        for (int jj = 0; jj < 32; jj++) {
            float4 w0 = *(const float4*)(Ws + jj * 128 + cA);
            float4 w1 = *(const float4*)(Ws + jj * 128 + cA + 64);
            float xr[8];
#pragma unroll
            for (int i2 = 0; i2 < 4; i2++) {
                xr[i2]     = Xs[(rA + i2) * 36 + jj];
                xr[4 + i2] = Xs[(rA + i2 + 64) * 36 + jj];
            }
#pragma unroll
            for (int i2 = 0; i2 < 8; i2++) {
                float xv = xr[i2];
                acc[i2][0] = fmaf(xv, w0.x, acc[i2][0]);
                acc[i2][1] = fmaf(xv, w0.y, acc[i2][1]);
                acc[i2][2] = fmaf(xv, w0.z, acc[i2][2]);
                acc[i2][3] = fmaf(xv, w0.w, acc[i2][3]);
                acc[i2][4] = fmaf(xv, w1.x, acc[i2][4]);
                acc[i2][5] = fmaf(xv, w1.y, acc[i2][5]);
                acc[i2][6] = fmaf(xv, w1.z, acc[i2][6]);
                acc[i2][7] = fmaf(xv, w1.w, acc[i2][7]);
            }
        }
        __syncthreads();
    }
#pragma unroll
    for (int i = 0; i < 8; i++) {
        int r = (i < 4) ? (rA + i) : (rA + i + 60);
#pragma unroll
        for (int chh = 0; chh < 2; chh++) {
            int c = cA + chh * 64;
            *(float4*)(out + (size_t)r * 256 + c) =
                make_float4(acc[i][chh * 4 + 0], acc[i][chh * 4 + 1],
                            acc[i][chh * 4 + 2], acc[i][chh * 4 + 3]);
        }
    }
}
__global__ void combine_bias(const float* __restrict__ eb2,
                             const float* __restrict__ Wke,
                             const float* __restrict__ Wve,
                             float* __restrict__ cb) {
    int x = blockIdx.x;
    int li = x & 7, kv = x >> 3;
    int l = li < 4 ? li : li + 1;
    int g = (li & 3) + 1;
    const float* Wp = (kv ? Wve : Wke) + (size_t)l * 16384;
    const float* eb = eb2 + g * 128;
    int cc = threadIdx.x;
    float a = 0.f;
    for (int j = 0; j < 128; j++) a = fmaf(eb[j], Wp[(size_t)j * 128 + cc], a);
    cb[l * 256 + kv * 128 + cc] = a;
}

// ============================ CSR construction =============================
__global__ void zero_i32(int* __restrict__ p, int n) {
    int i = blockIdx.x * 256 + threadIdx.x;
    if (i < n) p[i] = 0;
}
__global__ void hist_kernel(const int* __restrict__ dst, int E, int* __restrict__ deg) {
    int e = blockIdx.x * 256 + threadIdx.x;
    if (e < E) atomicAdd(&deg[dst[e]], 1);
}
__global__ __launch_bounds__(256) void exscan5(const int* __restrict__ deg0,
                                               int* __restrict__ off0,
                                               int* __restrict__ cursor0, int n) {
    int g = blockIdx.x;
    const int* deg = deg0 + (size_t)g * n;
    int* off = off0 + (size_t)g * (n + 1);
    int* cursor = cursor0 + (size_t)g * n;
    __shared__ int wsum[4];
    __shared__ int carry;
    int tid = threadIdx.x, lane = tid & 63, w = tid >> 6;
    if (tid == 0) carry = 0;
    __syncthreads();
    for (int base = 0; base < n; base += 256) {
        int v = (base + tid < n) ? deg[base + tid] : 0;
        int incl = v;
        for (int d = 1; d < 64; d <<= 1) {
            int t = __shfl_up(incl, d, 64);
            if (lane >= d) incl += t;
        }
        if (lane == 63) wsum[w] = incl;
        __syncthreads();
        int woff = 0;
        for (int i = 0; i < w; i++) woff += wsum[i];
        int total = wsum[0] + wsum[1] + wsum[2] + wsum[3];
        int excl = carry + woff + incl - v;
        if (base + tid < n) { off[base + tid] = excl; cursor[base + tid] = excl; }
        __syncthreads();
        if (tid == 0) carry += total;
        __syncthreads();
    }
    if (threadIdx.x == 0) off[n] = carry;
}
__global__ void scatter_kernel(const int* __restrict__ dst, int E,
                               int* __restrict__ cursor, int* __restrict__ eids) {
    int e = blockIdx.x * 256 + threadIdx.x;
    if (e < E) { int p = atomicAdd(&cursor[dst[e]], 1); eids[p] = e; }
}
__global__ void sort_edges(const int* __restrict__ eid, const int* __restrict__ srcArr,
                           const float* __restrict__ attr, int aw, int E,
                           int* __restrict__ esrc, float4* __restrict__ eattr) {
    int pos = blockIdx.x * 256 + threadIdx.x;
    if (pos >= E) return;
    int e = eid[pos];
    esrc[pos] = srcArr[e];
    if (attr) {
        float4 v;
        v.x = attr[(size_t)e * aw + 0];
        v.y = attr[(size_t)e * aw + 1];
        v.z = (aw > 2) ? attr[(size_t)e * aw + 2] : 0.f;
        v.w = (aw > 3) ? attr[(size_t)e * aw + 3] : 0.f;
        eattr[pos] = v;
    }
}

// ====== degree-sorted dst order: LDS-hierarchical counting sort, 33 bins ===
__global__ __launch_bounds__(256) void hist_deg2(const int* __restrict__ deg5, int n,
                                                 int* __restrict__ bh) {
    int g = blockIdx.y;
    const int* deg = deg5 + (size_t)g * n;
    __shared__ int lh[33];
    if (threadIdx.x < 33) lh[threadIdx.x] = 0;
    __syncthreads();
    int d = blockIdx.x * 256 + threadIdx.x;
    if (d < n) { int b = deg[d]; if (b > 32) b = 32; atomicAdd(&lh[b], 1); }
    __syncthreads();
    if (threadIdx.x < 33)
        bh[((size_t)g * NB_ + blockIdx.x) * 33 + threadIdx.x] = lh[threadIdx.x];
}
__global__ __launch_bounds__(64) void scan_bh(int* __restrict__ bh) {
    int g = blockIdx.x;
    int* p = bh + (size_t)g * NB_ * 33;
    __shared__ int tot[33], base[33];
    int bin = threadIdx.x;
    if (bin < 33) {
        int t = 0;
        for (int b = 0; b < NB_; b++) t += p[b * 33 + bin];
        tot[bin] = t;
    }
    __syncthreads();
    if (threadIdx.x == 0) {
        int acc = 0;
        for (int i = 0; i < 33; i++) { base[i] = acc; acc += tot[i]; }
    }
    __syncthreads();
    if (bin < 33) {
        int run = base[bin];
        for (int b = 0; b < NB_; b++) { int v = p[b * 33 + bin]; p[b * 33 + bin] = run; run += v; }
    }
}
__global__ __launch_bounds__(256) void scatter_ord2(const int* __restrict__ deg5, int n,
                                                    const int* __restrict__ bh,
                                                    int* __restrict__ dord5) {
    int g = blockIdx.y;
    const int* deg = deg5 + (size_t)g * n;
    int* dord = dord5 + (size_t)g * n;
    __shared__ int cur[33];
    if (threadIdx.x < 33)
        cur[threadIdx.x] = bh[((size_t)g * NB_ + blockIdx.x) * 33 + threadIdx.x];
    __syncthreads();
    int d = blockIdx.x * 256 + threadIdx.x;
    if (d < n) {
        int b = deg[d]; if (b > 32) b = 32;
        int p = atomicAdd(&cur[b], 1);
        dord[p] = d;
    }
}

// ====== prep_g: g[d][cp][h] = bf16( 0.25*sum_t Ck[cp][16h+t] q[d][16h+t] ) =
__global__ __launch_bounds__(256) void prep_g(const float* __restrict__ q,
                                              const float* __restrict__ cWl,
                                              const float* __restrict__ cbl,
                                              ushort* __restrict__ g,
                                              float* __restrict__ sb) {
    __shared__ float qs[8 * 132];
    int tid = threadIdx.x;
    int cp = tid & 127, hb = (tid >> 7) * 4;     // hb in {0,4}, wave-uniform
    float ck[64];
    {
        const float* csrc = cWl + (size_t)cp * 256 + hb * 16;
#pragma unroll
        for (int t4 = 0; t4 < 16; t4++) {
            float4 v = *(const float4*)(csrc + t4 * 4);
            ck[t4 * 4 + 0] = v.x; ck[t4 * 4 + 1] = v.y;
            ck[t4 * 4 + 2] = v.z; ck[t4 * 4 + 3] = v.w;
        }
    }
    int d0 = blockIdx.x * 8;
    {
        int dl = tid >> 5, col = (tid & 31) * 4;
        *(float4*)(qs + dl * 132 + col) = *(const float4*)(q + (size_t)(d0 + dl) * 128 + col);
    }
    __syncthreads();
#pragma unroll
    for (int dl = 0; dl < 8; dl++) {
        const float* qr = qs + dl * 132 + hb * 16;   // broadcast reads
        float a0 = 0.f, a1 = 0.f, a2 = 0.f, a3 = 0.f;
#pragma unroll
        for (int t = 0; t < 16; t++) {
            a0 = fmaf(ck[t],      qr[t],      a0);
            a1 = fmaf(ck[16 + t], qr[16 + t], a1);
            a2 = fmaf(ck[32 + t], qr[32 + t], a2);
            a3 = fmaf(ck[48 + t], qr[48 + t], a3);
        }
        ushort4 o = make_ushort4(f2bh(a0 * 0.25f), f2bh(a1 * 0.25f),
                                 f2bh(a2 * 0.25f), f2bh(a3 * 0.25f));
        *(ushort4*)(g + (size_t)(d0 + dl) * 1024 + cp * 8 + hb) = o;
    }
    if (tid < 64) {
        int dl = tid >> 3, h = tid & 7;
        const float* qr = qs + dl * 132 + h * 16;
        const float* cbr = cbl + h * 16;
        float a = 0.f;
#pragma unroll
        for (int t = 0; t < 16; t++) a = fmaf(cbr[t], qr[t], a);
        sb[(d0 + dl) * 8 + h] = a * 0.25f;
    }
}

// ===== fused attention + Cv epilogue: one wave per dst, writes agg =========
static constexpr int HS_ = 136;   // padded h-stride: conflict-free hstage access
__global__ __launch_bounds__(256) void attn_fact(const int* __restrict__ dord,
                                                 const int* __restrict__ off,
                                                 const int* __restrict__ esrc,
                                                 const float4* __restrict__ eattr,
                                                 const ushort* __restrict__ g,
                                                 const float* __restrict__ sb,
                                                 const float* __restrict__ eW1,
                                                 const float* __restrict__ eb1,
                                                 const float* __restrict__ q,
                                                 const ushort* __restrict__ kvp,
                                                 const float* __restrict__ cWl,
                                                 const float* __restrict__ cbl,
                                                 float* __restrict__ agg) {
    __shared__ float hw4[4 * 144];
    __shared__ float hstage[4][8 * HS_];
    __shared__ float vstage[4][128];
    __shared__ float dens2[4][8];
    __shared__ float part[2][4][128];
    __shared__ int sD[4];
    int w = threadIdx.x >> 6, l = threadIdx.x & 63;
    int i = l & 15, hlo = l >> 4;
    float* hw = hw4 + w * 144;   // [0..127] h_e, [128..135] w bcast
    int d = dord[blockIdx.x * 4 + w];
    int beg = off[d], end = off[d + 1];
    float q0 = q[(size_t)d * 128 + l] * 0.25f;
    float q1 = q[(size_t)d * 128 + 64 + l] * 0.25f;
    float gA[8], gB[8];
#pragma unroll
    for (int j = 0; j < 8; j++) {
        gA[j] = bh2f(g[(size_t)d * 1024 + (j * 16 + i) * 8 + hlo]);
        gB[j] = bh2f(g[(size_t)d * 1024 + (j * 16 + i) * 8 + hlo + 4]);
    }
    float sbA = sb[d * 8 + hlo], sbB = sb[d * 8 + 4 + hlo];
    float w1a[4], w1b[4];
#pragma unroll
    for (int j = 0; j < 4; j++) { w1a[j] = eW1[j * 128 + l]; w1b[j] = eW1[j * 128 + 64 + l]; }
    float ebA = eb1[l], ebB = eb1[64 + l];
    float dnA = 0.f, dnB = 0.f;
    float accL[8] = {}, accH[8] = {};
    float va0 = 0.f, va1 = 0.f;
    // 2-deep prefetch pipeline; keep raw ushorts (convert at use)
    float4 atA = make_float4(0.f, 0.f, 0.f, 0.f), atB = atA;
    ushort kA0 = 0, kA1 = 0, vA0 = 0, vA1 = 0;
    ushort kB0 = 0, kB1 = 0, vB0 = 0, vB1 = 0;
    auto LOADE = [&](int p, float4& at, ushort& ka, ushort& kb, ushort& va, ushort& vb) {
        int s = esrc[p]; at = eattr[p];
        const ushort* r = kvp + (size_t)s * 256;
        ka = r[l]; kb = r[64 + l];
        va = r[128 + l]; vb = r[192 + l];
    };
    if (beg < end) LOADE(beg, atA, kA0, kA1, vA0, vA1);
    if (beg + 1 < end) LOADE(beg + 1, atB, kB0, kB1, vB0, vB1);
    for (int pos = beg; pos < end; pos++) {
        float4 at = atA;
        ushort rk0 = kA0, rk1 = kA1, rv0 = vA0, rv1 = vA1;
        atA = atB; kA0 = kB0; kA1 = kB1; vA0 = vB0; vA1 = vB1;
        if (pos + 2 < end) LOADE(pos + 2, atB, kB0, kB1, vB0, vB1);
        float h0 = fmaxf(ebA + at.x * w1a[0] + at.y * w1a[1] + at.z * w1a[2] + at.w * w1a[3], 0.f);
        float h1 = fmaxf(ebB + at.x * w1b[0] + at.y * w1b[1] + at.z * w1b[2] + at.w * w1b[3], 0.f);
        hw[l] = h0; hw[64 + l] = h1;
        __builtin_amdgcn_wave_barrier();
        float pA = q0 * bh2f(rk0), pB = q1 * bh2f(rk1);
#pragma unroll
        for (int j = 0; j < 8; j++) {
            float hv = hw[j * 16 + i];
            pA = fmaf(hv, gA[j], pA);
            pB = fmaf(hv, gB[j], pB);
        }
#pragma unroll
        for (int msk = 1; msk < 16; msk <<= 1) {
            pA += __shfl_xor(pA, msk, 64);
            pB += __shfl_xor(pB, msk, 64);
        }
        // scores are provably tiny (|s| << 80): softmax without max-shift
        float wA = __expf(pA + sbA);
        float wB = __expf(pB + sbB);
        dnA += wA; dnB += wB;
        va0 = fmaf(wA, bh2f(rv0), va0);
        va1 = fmaf(wB, bh2f(rv1), va1);
        if (i == 0) { hw[128 + hlo] = wA; hw[132 + hlo] = wB; }
        __builtin_amdgcn_wave_barrier();
        float4 WA = *(float4*)(hw + 128), WB = *(float4*)(hw + 132);
#pragma unroll
        for (int j = 0; j < 4; j++) {
            float wa = ((const float*)&WA)[j];
            float wb = ((const float*)&WB)[j];
            accL[j]     = fmaf(wa, h0, accL[j]);
            accH[j]     = fmaf(wa, h1, accH[j]);
            accL[4 + j] = fmaf(wb, h0, accL[4 + j]);
            accH[4 + j] = fmaf(wb, h1, accH[4 + j]);
        }
    }
    // stage per-dst state to LDS (padded h-stride HS_ = conflict-free)
#pragma unroll
    for (int h = 0; h < 8; h++) {
        hstage[w][h * HS_ + l]      = accL[h];
        hstage[w][h * HS_ + 64 + l] = accH[h];
    }
    vstage[w][l] = va0; vstage[w][64 + l] = va1;
    if (i == 0) { dens2[w][hlo] = dnA; dens2[w][4 + hlo] = dnB; }
    if (l == 0) sD[w] = d;
    __syncthreads();
    // epilogue pass 1: cp split across 2 halves; each Cv element loaded once,
    // used for all 4 dsts -> 64-deep load chain, 4 FMA per load.
    {
        int cc = threadIdx.x & 127, h2 = threadIdx.x >> 7;
        int hh = cc >> 4;
        int cp0 = h2 * 64;
        const float* cvp = cWl + 128 + cc + (size_t)cp0 * 256;
        const float* h0p = &hstage[0][hh * HS_ + cp0];
        const float* h1p = &hstage[1][hh * HS_ + cp0];
        const float* h2p = &hstage[2][hh * HS_ + cp0];
        const float* h3p = &hstage[3][hh * HS_ + cp0];
        float p0 = 0.f, p1 = 0.f, p2 = 0.f, p3 = 0.f;
#pragma unroll 8
        for (int cp = 0; cp < 64; cp++) {
            float cv = cvp[(size_t)cp * 256];
            p0 = fmaf(h0p[cp], cv, p0);
            p1 = fmaf(h1p[cp], cv, p1);
            p2 = fmaf(h2p[cp], cv, p2);
            p3 = fmaf(h3p[cp], cv, p3);
        }
        part[h2][0][cc] = p0; part[h2][1][cc] = p1;
        part[h2][2][cc] = p2; part[h2][3][cc] = p3;
    }
    __syncthreads();
    // epilogue pass 2: combine halves, normalize, write 2 dsts per thread
    {
        int cc = threadIdx.x & 127, h2 = threadIdx.x >> 7;
        int hh = cc >> 4;
        float cvb = cbl[128 + cc];
#pragma unroll
        for (int t = 0; t < 2; t++) {
            int ds = h2 * 2 + t;
            float dn = dens2[ds][hh];
            float inv = 1.f / (dn + 1e-9f);
            float cf = dn * inv;
            float a = part[0][ds][cc] + part[1][ds][cc];
            agg[(size_t)sD[ds] * 128 + cc] = (vstage[ds][cc] + a) * inv + cvb * cf;
        }
    }
}

// ===== plain fused attention (no-max softmax, bf16 kv, deg-sorted) =========
__global__ __launch_bounds__(256) void attn_plain(const int* __restrict__ dord,
                                                  const int* __restrict__ off,
                                                  const int* __restrict__ esrc,
                                                  const float* __restrict__ q,
                                                  const ushort* __restrict__ kvp,
                                                  float* __restrict__ agg) {
    int lane = threadIdx.x & 63;
    int d = dord[blockIdx.x * 4 + (threadIdx.x >> 6)];
    int beg = off[d], end = off[d + 1];
    float q0 = q[(size_t)d * 128 + lane] * 0.25f;
    float q1 = q[(size_t)d * 128 + 64 + lane] * 0.25f;
    float den0 = 0.f, den1 = 0.f, acc0 = 0.f, acc1 = 0.f;
    ushort kA0 = 0, kA1 = 0, vA0 = 0, vA1 = 0;
    ushort kB0 = 0, kB1 = 0, vB0 = 0, vB1 = 0;
    auto LOADE = [&](int p, ushort& ka, ushort& kb, ushort& va, ushort& vb) {
        int s = esrc[p];
        const ushort* r = kvp + (size_t)s * 256;
        ka = r[lane]; kb = r[64 + lane];
        va = r[128 + lane]; vb = r[192 + lane];
    };
    if (beg < end) LOADE(beg, kA0, kA1, vA0, vA1);
    if (beg + 1 < end) LOADE(beg + 1, kB0, kB1, vB0, vB1);
    for (int pos = beg; pos < end; pos++) {
        ushort rk0 = kA0, rk1 = kA1, rv0 = vA0, rv1 = vA1;
        kA0 = kB0; kA1 = kB1; vA0 = vB0; vA1 = vB1;
        if (pos + 2 < end) LOADE(pos + 2, kB0, kB1, vB0, vB1);
        float p0 = q0 * bh2f(rk0), p1 = q1 * bh2f(rk1);
#pragma unroll
        for (int msk = 1; msk < 16; msk <<= 1) {
            p0 += __shfl_xor(p0, msk, 64);
            p1 += __shfl_xor(p1, msk, 64);
        }
        float w0 = __expf(p0), w1 = __expf(p1);
        den0 += w0; den1 += w1;
        acc0 = fmaf(w0, bh2f(rv0), acc0);
        acc1 = fmaf(w1, bh2f(rv1), acc1);
    }
    agg[(size_t)d * 128 + lane]      = acc0 / (den0 + 1e-9f);
    agg[(size_t)d * 128 + 64 + lane] = acc1 / (den1 + 1e-9f);
}

// ======================= small glue kernels ================================
__global__ void mode_init(float* __restrict__ m, const float* __restrict__ mt) {
    int idx = blockIdx.x * 256 + threadIdx.x;
    if (idx >= M_ * H_) return;
    int node = idx >> 7, c = idx & 127;
    m[idx] = mt[(node % K_) * H_ + c];
}
__global__ void extract_last(const float* __restrict__ m, float* __restrict__ out) {
    int idx = blockIdx.x * 256 + threadIdx.x;
    if (idx >= AK_ * H_) return;
    int row = idx >> 7, c = idx & 127;
    int a = row / K_, k = row - a * K_;
    int node = (a * T_ + (T_ - 1)) * K_ + k;
    out[idx] = m[(size_t)node * H_ + c];
}
__global__ void add_anchor(float* __restrict__ m, const float* __restrict__ anchor) {
    int idx = blockIdx.x * 256 + threadIdx.x;
    if (idx >= M_ * H_) return;
    int node = idx >> 7, c = idx & 127;
    int a = node / (T_ * K_), k = node % K_;
    m[idx] += anchor[(size_t)(a * K_ + k) * H_ + c];
}

// ============================ host launch ==================================
extern "C" void kernel_launch(void* const* d_in, const int* in_sizes, int n_in,
                              void* d_out, int out_size, void* d_ws, size_t ws_size,
                              hipStream_t stream) {
    const float* a_input     = (const float*)d_in[0];
    const float* l_embs      = (const float*)d_in[1];
    const float* mode_tokens = (const float*)d_in[2];
    const float* emb_W1 = (const float*)d_in[3];
    const float* emb_b1 = (const float*)d_in[4];
    const float* emb_W2 = (const float*)d_in[5];
    const float* emb_b2 = (const float*)d_in[6];
    const float* ga_Wq  = (const float*)d_in[7];
    const float* ga_Wk  = (const float*)d_in[8];
    const float* ga_Wv  = (const float*)d_in[9];
    const float* ga_Wo  = (const float*)d_in[10];
    const float* ga_Wke = (const float*)d_in[11];
    const float* ga_Wve = (const float*)d_in[12];
    const float* ga_g1  = (const float*)d_in[13];
    const float* ga_b1  = (const float*)d_in[14];
    const float* ga_g2  = (const float*)d_in[15];
    const float* ga_b2  = (const float*)d_in[16];
    const float* ga_fW1 = (const float*)d_in[17];
    const float* ga_fb1 = (const float*)d_in[18];
    const float* ga_fW2 = (const float*)d_in[19];
    const float* ga_fb2 = (const float*)d_in[20];
    const float* tp_W1 = (const float*)d_in[21];
    const float* tp_b1 = (const float*)d_in[22];
    const float* tp_W2 = (const float*)d_in[23];
    const float* tp_b2 = (const float*)d_in[24];
    const float* pa_W1 = (const float*)d_in[25];
    const float* pa_b1 = (const float*)d_in[26];
    const float* pa_W2 = (const float*)d_in[27];
    const float* pa_b2 = (const float*)d_in[28];
    const float* tr_W1 = (const float*)d_in[29];
    const float* tr_b1 = (const float*)d_in[30];
    const float* tr_W2 = (const float*)d_in[31];
    const float* tr_b2 = (const float*)d_in[32];
    const float* attrs[4] = { (const float*)d_in[33], (const float*)d_in[34],
                              (const float*)d_in[35], (const float*)d_in[36] };
    const int* eis[5] = { (const int*)d_in[37], (const int*)d_in[38], (const int*)d_in[39],
                          (const int*)d_in[40], (const int*)d_in[41] };
    int Es[5];
    int Emax = 0;
    for (int i = 0; i < 5; i++) { Es[i] = in_sizes[37 + i] / 2; if (Es[i] > Emax) Emax = Es[i]; }

    size_t off = 0;
    auto alloc = [&](size_t nbytes) -> char* {
        char* p = (char*)d_ws + off;
        off += ((nbytes + 255) / 256) * 256;
        return p;
    };
    float* cW     = (float*)alloc((size_t)NL_ * 128 * 256 * 4);
    float* cb     = (float*)alloc((size_t)NL_ * 256 * 4);
    ushort* wbh   = (ushort*)alloc((size_t)NL_ * WLAY * 2);
    ushort* wbl   = (ushort*)alloc((size_t)NL_ * WLAY * 2);
    float* a_embs = (float*)alloc((size_t)AT_ * H_ * 4);
    float* m      = (float*)alloc((size_t)M_ * H_ * 4);
    float* q      = (float*)alloc((size_t)M_ * H_ * 4);
    ushort* kvb   = (ushort*)alloc((size_t)M_ * 256 * 2);    // bf16 k|v fused
    float* agg    = (float*)alloc((size_t)M_ * H_ * 4);
    float* big    = (float*)alloc((size_t)M_ * FF_ * 4);     // FFN hidden
    ushort* gbuf  = (ushort*)alloc((size_t)M_ * 1024 * 2);   // bf16 g [d][cp][h]
    float* sb     = (float*)alloc((size_t)M_ * 8 * 4);
    float* muM    = (float*)alloc((size_t)M_ * 4);
    float* rsM    = (float*)alloc((size_t)M_ * 4);
    float* muA    = (float*)alloc((size_t)AT_ * 4);
    float* rsA    = (float*)alloc((size_t)AT_ * 4);
    float* muL    = (float*)alloc((size_t)L_ * 4);
    float* rsL    = (float*)alloc((size_t)L_ * 4);
    int* csr_off  = (int*)alloc((size_t)5 * (M_ + 1) * 4);
    int* csr_eid  = (int*)alloc((size_t)5 * Emax * 4);
    int* esrc     = (int*)alloc((size_t)5 * Emax * 4);
    float4* eattr = (float4*)alloc((size_t)4 * Emax * 16);
    int* deg5     = (int*)alloc((size_t)5 * M_ * 4);
    int* cursor5  = (int*)alloc((size_t)5 * M_ * 4);
    int* dord5    = (int*)alloc((size_t)5 * M_ * 4);
    int* bh5      = (int*)alloc((size_t)5 * NB_ * 33 * 4);
    float* mlast  = (float*)alloc((size_t)AK_ * H_ * 4);
    float* hbuf   = (float*)alloc((size_t)AK_ * H_ * 4);
    float* anchor = (float*)alloc((size_t)AK_ * H_ * 4);
    (void)ws_size; (void)n_in;

    float* outp = (float*)d_out;

    // ---- CSR + sorted src/attr + degree-sorted dst order for 5 graphs ----
    zero_i32<<<(5 * M_ + 255) / 256, 256, 0, stream>>>(deg5, 5 * M_);
    for (int gI = 0; gI < 5; gI++)
        hist_kernel<<<(Es[gI] + 255) / 256, 256, 0, stream>>>(eis[gI] + Es[gI], Es[gI], deg5 + (size_t)gI * M_);
    exscan5<<<5, 256, 0, stream>>>(deg5, csr_off, cursor5, M_);
    for (int gI = 0; gI < 5; gI++)
        scatter_kernel<<<(Es[gI] + 255) / 256, 256, 0, stream>>>(eis[gI] + Es[gI], Es[gI],
            cursor5 + (size_t)gI * M_, csr_eid + (size_t)gI * Emax);
    for (int gI = 0; gI < 5; gI++) {
        int aw = (gI == 0 || gI == 2) ? 4 : (gI == 4 ? 0 : 3);
        sort_edges<<<(Es[gI] + 255) / 256, 256, 0, stream>>>(
            csr_eid + (size_t)gI * Emax, eis[gI], (gI < 4) ? attrs[gI] : nullptr, aw, Es[gI],
            esrc + (size_t)gI * Emax, eattr + (size_t)gI * Emax);
    }
    hist_deg2<<<dim3(NB_, 5), 256, 0, stream>>>(deg5, M_, bh5);
    scan_bh<<<5, 64, 0, stream>>>(bh5);
    scatter_ord2<<<dim3(NB_, 5), 256, 0, stream>>>(deg5, M_, bh5, dord5);

    // ---- weight prep ----
    prep_w<<<dim3(192, 10), 256, 0, stream>>>(ga_Wq, ga_Wk, ga_Wv, ga_Wo, ga_fW1, ga_fW2, wbh, wbl);
    combine_fast<<<16, 256, 0, stream>>>(emb_W2, ga_Wke, ga_Wve, cW);
    combine_bias<<<16, 128, 0, stream>>>(emb_b2, ga_Wke, ga_Wve, cb);

    // ---- embeddings / init ----
    small_gemm<1, false><<<(AT_ * H_ + 255) / 256, 256, 0, stream>>>(a_input, emb_W1, emb_b1, nullptr, big, AT_, 5, H_);
    small_gemm<0, false><<<(AT_ * H_ + 255) / 256, 256, 0, stream>>>(big, emb_W2, emb_b2, nullptr, a_embs, AT_, H_, H_);
    mode_init<<<(M_ * H_ + 255) / 256, 256, 0, stream>>>(m, mode_tokens);
    ln_stats<<<M_ / 4, 256, 0, stream>>>(m, muM, rsM, M_);
    ln_stats<<<AT_ / 4, 256, 0, stream>>>(a_embs, muA, rsA, AT_);
    ln_stats<<<L_ / 4, 256, 0, stream>>>(l_embs, muL, rsL, L_);

    struct Cfg { const float* srcX; const float* muS; const float* rsS; int n_src; int gi; bool hasE; };
    Cfg cfgs[10] = {
        { a_embs, muA, rsA, AT_, 0, true }, { l_embs, muL, rsL, L_, 1, true },
        { nullptr, nullptr, nullptr, M_, 2, true }, { nullptr, nullptr, nullptr, M_, 3, true },
        { nullptr, nullptr, nullptr, M_, 4, false },
        { a_embs, muA, rsA, AT_, 0, true }, { l_embs, muL, rsL, L_, 1, true },
        { nullptr, nullptr, nullptr, M_, 2, true }, { nullptr, nullptr, nullptr, M_, 3, true },
        { nullptr, nullptr, nullptr, M_, 4, false },
    };

    for (int l = 0; l < 10; l++) {
        const Cfg& cf = cfgs[l];
        const int* offg = csr_off + cf.gi * (M_ + 1);
        const int* esrcg = esrc + (size_t)cf.gi * Emax;
        const float4* eattrg = eattr + (size_t)cf.gi * Emax;
        const int* dordg = dord5 + (size_t)cf.gi * M_;
        const float* g1 = ga_g1 + l * H_; const float* b1 = ga_b1 + l * H_;
        size_t wb = (size_t)l * WLAY;

        // muM/rsM currently hold LN1 stats of m (from prev FFN2 STATS / init)
        if (cf.srcX) {
            mgemm<0, false, 0, true, false><<<dim3(M_ / 128, 1), 256, 0, stream>>>(
                m, wbh + wb, wbl + wb, nullptr, nullptr, q, nullptr,
                muM, rsM, g1, b1, nullptr, nullptr, M_, 128, 128);
            mgemm<0, false, 1, true, false><<<dim3(cf.n_src / 128, 2), 256, 0, stream>>>(
                cf.srcX, wbh + wb + 16384, wbl + wb + 16384, nullptr, nullptr, nullptr, kvb,
                cf.muS, cf.rsS, g1, b1, nullptr, nullptr, cf.n_src, 128, 256);
        } else {
            mgemm<0, false, 2, true, false><<<dim3(M_ / 128, 3), 256, 0, stream>>>(
                m, wbh + wb, wbl + wb, nullptr, nullptr, q, kvb,
                muM, rsM, g1, b1, nullptr, nullptr, M_, 128, 384);
        }

        if (cf.hasE) {
            int gg = (l < 5) ? l + 1 : l - 4;
            const float* eW1g = emb_W1 + (size_t)gg * 5 * H_;
            const float* eb1g = emb_b1 + (size_t)gg * H_;
            prep_g<<<M_ / 8, 256, 0, stream>>>(q, cW + (size_t)l * 32768, cb + l * 256, gbuf, sb);
            attn_fact<<<M_ / 4, 256, 0, stream>>>(dordg, offg, esrcg, eattrg, gbuf, sb, eW1g, eb1g,
                                                  q, kvb, cW + (size_t)l * 32768, cb + l * 256, agg);
        } else {
            attn_plain<<<M_ / 4, 256, 0, stream>>>(dordg, offg, esrcg, q, kvb, agg);
        }

        // m += agg @ Wo   (+ LN2 stats fused)
        mgemm<0, true, 0, false, true><<<dim3(M_ / 128, 1), 256, 0, stream>>>(
            agg, wbh + wb + 49152, wbl + wb + 49152, nullptr, m, m, nullptr,
            nullptr, nullptr, nullptr, nullptr, muM, rsM, M_, 128, 128);
        // FFN with fused LN2
        mgemm<1, false, 0, true, false><<<dim3(M_ / 128, 4), 256, 0, stream>>>(
            m, wbh + wb + 65536, wbl + wb + 65536, ga_fb1 + l * FF_, nullptr, big, nullptr,
            muM, rsM, ga_g2 + l * H_, ga_b2 + l * H_, nullptr, nullptr, M_, 128, 512);
        // FFN2 (+ next-layer LN1 stats fused)
        mgemm<0, true, 0, false, true><<<dim3(M_ / 128, 1), 256, 0, stream>>>(
            big, wbh + wb + 131072, wbl + wb + 131072, ga_fb2 + l * H_, m, m, nullptr,
            nullptr, nullptr, nullptr, nullptr, muM, rsM, M_, 512, 128);

        if (l == 4) {
            extract_last<<<(AK_ * H_ + 255) / 256, 256, 0, stream>>>(m, mlast);
            small_gemm<1, false><<<(AK_ * H_ + 255) / 256, 256, 0, stream>>>(mlast, tp_W1, tp_b1, nullptr, hbuf, AK_, H_, H_);
            small_gemm<0, false><<<(AK_ * P2F + 255) / 256, 256, 0, stream>>>(hbuf, tp_W2, tp_b2, nullptr, outp, AK_, H_, P2F);
            small_gemm<1, false><<<(AK_ * H_ + 255) / 256, 256, 0, stream>>>(outp, pa_W1, pa_b1, nullptr, hbuf, AK_, P2F, H_);
            small_gemm<0, false><<<(AK_ * H_ + 255) / 256, 256, 0, stream>>>(hbuf, pa_W2, pa_b2, nullptr, anchor, AK_, H_, H_);
            add_anchor<<<(M_ * H_ + 255) / 256, 256, 0, stream>>>(m, anchor);
            ln_stats<<<M_ / 4, 256, 0, stream>>>(m, muM, rsM, M_);   // m changed
        }
    }

    extract_last<<<(AK_ * H_ + 255) / 256, 256, 0, stream>>>(m, mlast);
    small_gemm<1, false><<<(AK_ * H_ + 255) / 256, 256, 0, stream>>>(mlast, tr_W1, tr_b1, nullptr, hbuf, AK_, H_, H_);
    small_gemm<0, true><<<(AK_ * P2F + 255) / 256, 256, 0, stream>>>(hbuf, tr_W2, tr_b2, outp, outp + AK_ * P2F, AK_, H_, P2F);
}

// Round 17
// 2301.003 us; speedup vs baseline: 1.0491x; 1.0334x over previous
//
#include <hip/hip_runtime.h>
#include <hip/hip_bf16.h>
#include <math.h>

#define DEV __device__ __forceinline__

typedef __attribute__((ext_vector_type(4))) float floatx4;
typedef __attribute__((ext_vector_type(8))) __bf16 bf16x8;

static constexpr int A_ = 64, T_ = 50, K_ = 6, H_ = 128, NH_ = 8, F_ = 60, L_ = 512;
static constexpr int M_  = A_ * T_ * K_;   // 19200 mode nodes
static constexpr int AT_ = A_ * T_;        // 3200
static constexpr int FF_ = 4 * H_;         // 512
static constexpr int NL_ = 10;
static constexpr int P2F = 2 * F_;         // 120
static constexpr int AK_ = A_ * K_;        // 384
static constexpr size_t WLAY = 196608;     // per-layer transposed-weight elems
static constexpr int NB_ = (M_ + 255) / 256;  // 75 blocks for M-sized grids

// ---- bf16 split helpers ----
DEV ushort f2bh(float f) {                 // RNE float->bf16 bits
    unsigned u = __float_as_uint(f);
    unsigned r = u + 0x7FFFu + ((u >> 16) & 1u);
    return (ushort)(r >> 16);
}
DEV float bh2f(ushort h) { return __uint_as_float(((unsigned)h) << 16); }

// ============ ln_stats: per-row mean / rsqrt(var+eps), one wave per row ====
__global__ __launch_bounds__(256) void ln_stats(const float* __restrict__ x,
                                                float* __restrict__ mu,
                                                float* __restrict__ rs, int n) {
    int row = blockIdx.x * 4 + (threadIdx.x >> 6);
    int lane = threadIdx.x & 63;
    if (row >= n) return;
    const float* xr = x + (size_t)row * H_;
    float v0 = xr[lane], v1 = xr[lane + 64];
    float s = v0 + v1;
    for (int m = 32; m >= 1; m >>= 1) s += __shfl_xor(s, m, 64);
    float m_ = s * (1.f / 128.f);
    float d0 = v0 - m_, d1 = v1 - m_;
    float vs = d0 * d0 + d1 * d1;
    for (int m = 32; m >= 1; m >>= 1) vs += __shfl_xor(vs, m, 64);
    if (lane == 0) {
        mu[row] = m_;
        rs[row] = rsqrtf(vs * (1.f / 128.f) + 1e-5f);
    }
}

// ====== split-bf16 MFMA GEMM: Y = act(LN?(X) @ W + bias) (+res) ===========
// OMODE: 0 = f32 out (+RES), 1 = bf16 out, 2 = mixed (col-block 0 -> f32 Y
// stride 128; col-blocks 1,2 -> bf16 Yb stride 256). LNX: apply layernorm
// during staging (Kd==128). STATS: emit per-row mu/rs of the final output
// (requires OMODE 0, C==128, single col-block).
template <int ACT, bool RES, int OMODE, bool LNX, bool STATS>
__global__ __launch_bounds__(256) void mgemm(const float* __restrict__ X,
                                             const ushort* __restrict__ Wh,
                                             const ushort* __restrict__ Wl,
                                             const float* __restrict__ bias,
                                             const float* __restrict__ res,
                                             float* __restrict__ Y,
                                             ushort* __restrict__ Yb,
                                             const float* __restrict__ muv,
                                             const float* __restrict__ rsv,
                                             const float* __restrict__ lng,
                                             const float* __restrict__ lnb,
                                             float* __restrict__ muo,
                                             float* __restrict__ rso,
                                             int n, int Kd, int C) {
    __shared__ ushort lds[4 * 8192];           // Xh,Xl,Wsh,Wsl: [128][64] each
    ushort* Xh  = lds;
    ushort* Xl  = lds + 8192;
    ushort* Wsh = lds + 16384;
    ushort* Wsl = lds + 24576;
    int row0 = blockIdx.x * 128, col0 = blockIdx.y * 128;
    int tid = threadIdx.x;
    int lane = tid & 63, wid = tid >> 6;
    int rbase = (wid >> 1) * 64, cbase = (wid & 1) * 64;
    int lrow = lane & 15, lk = lane >> 4;
    floatx4 acc[4][4];
#pragma unroll
    for (int a = 0; a < 4; a++)
#pragma unroll
        for (int b2 = 0; b2 < 4; b2++) acc[a][b2] = floatx4{0.f, 0.f, 0.f, 0.f};

    for (int k0 = 0; k0 < Kd; k0 += 64) {
        float4 g4, b4;
        if (LNX) {
            int kcol = k0 + (tid & 15) * 4;
            g4 = *(const float4*)(lng + kcol);
            b4 = *(const float4*)(lnb + kcol);
        }
#pragma unroll
        for (int i = 0; i < 8; i++) {
            int idx = tid + i * 256;
            int r = idx >> 4, kc = idx & 15;
            float4 v = *(const float4*)(X + (size_t)(row0 + r) * Kd + k0 + kc * 4);
            if (LNX) {
                float mur = muv[row0 + r];
                float rsr = rsv[row0 + r];
                v.x = (v.x - mur) * rsr * g4.x + b4.x;
                v.y = (v.y - mur) * rsr * g4.y + b4.y;
                v.z = (v.z - mur) * rsr * g4.z + b4.z;
                v.w = (v.w - mur) * rsr * g4.w + b4.w;
            }
            ushort h0 = f2bh(v.x), h1 = f2bh(v.y), h2 = f2bh(v.z), h3 = f2bh(v.w);
            ushort l0 = f2bh(v.x - bh2f(h0)), l1 = f2bh(v.y - bh2f(h1)),
                   l2 = f2bh(v.z - bh2f(h2)), l3 = f2bh(v.w - bh2f(h3));
            int base = (r << 6) + (((kc >> 1) ^ (r & 7)) << 3) + ((kc & 1) << 2);
            *(ushort4*)(Xh + base) = make_ushort4(h0, h1, h2, h3);
            *(ushort4*)(Xl + base) = make_ushort4(l0, l1, l2, l3);
        }
#pragma unroll
        for (int i = 0; i < 4; i++) {
            int idx = tid + i * 256;
            int c = idx >> 3, ch = idx & 7;
            int base = (c << 6) + ((ch ^ (c & 7)) << 3);
            size_t go = (size_t)(col0 + c) * Kd + k0 + ch * 8;
            *(float4*)(Wsh + base) = *(const float4*)(Wh + go);
            *(float4*)(Wsl + base) = *(const float4*)(Wl + go);
        }
        __syncthreads();
#pragma unroll
        for (int kk = 0; kk < 2; kk++) {
            int ch = kk * 4 + lk;
            bf16x8 xh[4], xl[4], wh[4], wl[4];
#pragma unroll
            for (int s = 0; s < 4; s++) {
                int r = rbase + s * 16 + lrow;
                int xoff = (r << 6) + ((ch ^ (r & 7)) << 3);
                xh[s] = *(const bf16x8*)(Xh + xoff);
                xl[s] = *(const bf16x8*)(Xl + xoff);
                int c = cbase + s * 16 + lrow;
                int woff = (c << 6) + ((ch ^ (c & 7)) << 3);
                wh[s] = *(const bf16x8*)(Wsh + woff);
                wl[s] = *(const bf16x8*)(Wsl + woff);
            }
#pragma unroll
            for (int sr = 0; sr < 4; sr++)
#pragma unroll
                for (int sc = 0; sc < 4; sc++) {
                    acc[sr][sc] = __builtin_amdgcn_mfma_f32_16x16x32_bf16(wh[sc], xh[sr], acc[sr][sc], 0, 0, 0);
                    acc[sr][sc] = __builtin_amdgcn_mfma_f32_16x16x32_bf16(wl[sc], xh[sr], acc[sr][sc], 0, 0, 0);
                    acc[sr][sc] = __builtin_amdgcn_mfma_f32_16x16x32_bf16(wh[sc], xl[sr], acc[sr][sc], 0, 0, 0);
                }
        }
        __syncthreads();
    }
    float rowsum[4] = {}, rowsq[4] = {};
#pragma unroll
    for (int sr = 0; sr < 4; sr++) {
        int row = row0 + rbase + sr * 16 + lrow;
#pragma unroll
        for (int sc = 0; sc < 4; sc++) {
            int col = col0 + cbase + sc * 16 + lk * 4;
            float4 v = make_float4(acc[sr][sc][0], acc[sr][sc][1],
                                   acc[sr][sc][2], acc[sr][sc][3]);
            if (bias) { float4 bv = *(const float4*)(bias + col);
                        v.x += bv.x; v.y += bv.y; v.z += bv.z; v.w += bv.w; }
            if (ACT == 1) { v.x = fmaxf(v.x, 0.f); v.y = fmaxf(v.y, 0.f);
                            v.z = fmaxf(v.z, 0.f); v.w = fmaxf(v.w, 0.f); }
            if (OMODE == 0) {
                size_t o = (size_t)row * C + col;
                if (RES) { float4 rv = *(const float4*)(res + o);
                           v.x += rv.x; v.y += rv.y; v.z += rv.z; v.w += rv.w; }
                if (STATS) {
                    rowsum[sr] += v.x + v.y + v.z + v.w;
                    rowsq[sr]  += v.x * v.x + v.y * v.y + v.z * v.z + v.w * v.w;
                }
                *(float4*)(Y + o) = v;
            } else if (OMODE == 1) {
                size_t o = (size_t)row * C + col;
                *(ushort4*)(Yb + o) = make_ushort4(f2bh(v.x), f2bh(v.y), f2bh(v.z), f2bh(v.w));
            } else {
                if (col0 == 0) {
                    *(float4*)(Y + (size_t)row * 128 + col) = v;
                } else {
                    *(ushort4*)(Yb + (size_t)row * 256 + (col - 128)) =
                        make_ushort4(f2bh(v.x), f2bh(v.y), f2bh(v.z), f2bh(v.w));
                }
            }
        }
    }
    if (STATS) {
        float* sums = (float*)lds;            // [128][8]
        float* sqs  = ((float*)lds) + 1024;   // [128][8]
        int slot = (wid & 1) * 4 + lk;
#pragma unroll
        for (int sr = 0; sr < 4; sr++) {
            int rl = rbase + sr * 16 + lrow;
            sums[rl * 8 + slot] = rowsum[sr];
            sqs[rl * 8 + slot]  = rowsq[sr];
        }
        __syncthreads();
        if (tid < 128) {
            float s = 0.f, sq = 0.f;
#pragma unroll
            for (int t = 0; t < 8; t++) { s += sums[tid * 8 + t]; sq += sqs[tid * 8 + t]; }
            float mu = s * (1.f / 128.f);
            float var = sq * (1.f / 128.f) - mu * mu;
            muo[row0 + tid] = mu;
            rso[row0 + tid] = rsqrtf(var + 1e-5f);
        }
    }
}

// ==== prep_w: transpose+split all per-layer GEMM weights to bf16 [C][K] ====
__global__ __launch_bounds__(256) void prep_w(const float* __restrict__ Wq,
                                              const float* __restrict__ Wk,
                                              const float* __restrict__ Wv,
                                              const float* __restrict__ Wo,
                                              const float* __restrict__ fW1,
                                              const float* __restrict__ fW2,
                                              ushort* __restrict__ oh,
                                              ushort* __restrict__ ol) {
    int l = blockIdx.y, t = blockIdx.x;
    const float* src; int K, C, tiles_c; size_t obase;
    if (t < 64) {
        int mi = t >> 4; t &= 15;
        src = (mi == 0 ? Wq : mi == 1 ? Wk : mi == 2 ? Wv : Wo) + (size_t)l * 16384;
        K = 128; C = 128; tiles_c = 4; obase = (size_t)l * WLAY + (size_t)mi * 16384;
    } else if (t < 128) {
        t -= 64; src = fW1 + (size_t)l * 65536;
        K = 128; C = 512; tiles_c = 16; obase = (size_t)l * WLAY + 65536;
    } else {
        t -= 128; src = fW2 + (size_t)l * 65536;
        K = 512; C = 128; tiles_c = 4; obase = (size_t)l * WLAY + 131072;
    }
    int tc = t % tiles_c, tk = t / tiles_c;
    __shared__ float tile[32][33];
    int tx = threadIdx.x & 31, ty = threadIdx.x >> 5;
#pragma unroll
    for (int i = 0; i < 4; i++) {
        int k = tk * 32 + ty + i * 8;
        tile[ty + i * 8][tx] = src[(size_t)k * C + tc * 32 + tx];
    }
    __syncthreads();
#pragma unroll
    for (int i = 0; i < 4; i++) {
        int c = tc * 32 + ty + i * 8;
        float v = tile[tx][ty + i * 8];
        ushort h = f2bh(v);
        ushort lo = f2bh(v - bh2f(h));
        size_t o = obase + (size_t)c * K + tk * 32 + tx;
        oh[o] = h; ol[o] = lo;
    }
}

// ============== naive GEMM for small/ragged shapes =========================
template <int ACT, bool RES>
__global__ void small_gemm(const float* __restrict__ X, const float* __restrict__ W,
                           const float* __restrict__ bias, const float* __restrict__ res,
                           float* __restrict__ Y, int n, int Kd, int C) {
    int idx = blockIdx.x * 256 + threadIdx.x;
    if (idx >= n * C) return;
    int row = idx / C, c = idx - row * C;
    float a = bias ? bias[c] : 0.f;
    const float* xr = X + (size_t)row * Kd;
    for (int k = 0; k < Kd; k++) a = fmaf(xr[k], W[(size_t)k * C + c], a);
    if (ACT == 1) a = fmaxf(a, 0.f);
    if (RES) a += res[idx];
    Y[idx] = a;
}

// ==== combined weights cW[l][k][c256]: tiled f32 GEMM, 16 blocks ===========
__global__ __launch_bounds__(256) void combine_fast(const float* __restrict__ eW2,
                                                    const float* __restrict__ Wke,
                                                    const float* __restrict__ Wve,
                                                    float* __restrict__ cW) {
    __shared__ float Xs[128 * 36];
    __shared__ float Ws[32 * 128];
    int x = blockIdx.x;
    int li = x & 7, kv = x >> 3;
    int l = li < 4 ? li : li + 1;
    int g = (li & 3) + 1;
    const float* E2 = eW2 + (size_t)g * 16384;
    const float* Wp = (kv ? Wve : Wke) + (size_t)l * 16384;
    float* out = cW + (size_t)l * 32768 + kv * 128;
    int tid = threadIdx.x;
    int tc = tid & 15, tr = tid >> 4;
    int cA = tc * 4, rA = tr * 4;
    float acc[8][8] = {};
    for (int j0 = 0; j0 < 128; j0 += 32) {
#pragma unroll
        for (int i = 0; i < 4; i++) {
            int idx = tid + i * 256;
            int r = idx >> 3, jc = idx & 7;
            *(float4*)(Xs + r * 36 + jc * 4) =
                *(const float4*)(E2 + (size_t)r * 128 + j0 + jc * 4);
        }
#pragma unroll
        for (int i = 0; i < 4; i++) {
            int idx = tid + i * 256;
            int cc = idx & 31, jj = idx >> 5;
            *(float4*)(Ws + jj * 128 + cc * 4) =
                *(const float4*)(Wp + (size_t)(j0 + jj) * 128 + cc * 4);
        }
        __syncthreads();
#pragma unroll 8
        for (int jj = 0; jj < 32; jj++) {
            float4 w0 = *(const float4*)(Ws + jj * 128 + cA);
            float4 w1 = *(const float4*)(Ws + jj * 128 + cA + 64);
            float xr[8];
#pragma unroll
            for (int i2 = 0; i2 < 4; i2++) {
                xr[i2]     = Xs[(rA + i2) * 36 + jj];
                xr[4 + i2] = Xs[(rA + i2 + 64) * 36 + jj];
            }
#pragma unroll
            for (int i2 = 0; i2 < 8; i2++) {
                float xv = xr[i2];
                acc[i2][0] = fmaf(xv, w0.x, acc[i2][0]);
                acc[i2][1] = fmaf(xv, w0.y, acc[i2][1]);
                acc[i2][2] = fmaf(xv, w0.z, acc[i2][2]);
                acc[i2][3] = fmaf(xv, w0.w, acc[i2][3]);
                acc[i2][4] = fmaf(xv, w1.x, acc[i2][4]);
                acc[i2][5] = fmaf(xv, w1.y, acc[i2][5]);
                acc[i2][6] = fmaf(xv, w1.z, acc[i2][6]);
                acc[i2][7] = fmaf(xv, w1.w, acc[i2][7]);
            }
        }
        __syncthreads();
    }
#pragma unroll
    for (int i = 0; i < 8; i++) {
        int r = (i < 4) ? (rA + i) : (rA + i + 60);
#pragma unroll
        for (int chh = 0; chh < 2; chh++) {
            int c = cA + chh * 64;
            *(float4*)(out + (size_t)r * 256 + c) =
                make_float4(acc[i][chh * 4 + 0], acc[i][chh * 4 + 1],
                            acc[i][chh * 4 + 2], acc[i][chh * 4 + 3]);
        }
    }
}
__global__ void combine_bias(const float* __restrict__ eb2,
                             const float* __restrict__ Wke,
                             const float* __restrict__ Wve,
                             float* __restrict__ cb) {
    int x = blockIdx.x;
    int li = x & 7, kv = x >> 3;
    int l = li < 4 ? li : li + 1;
    int g = (li & 3) + 1;
    const float* Wp = (kv ? Wve : Wke) + (size_t)l * 16384;
    const float* eb = eb2 + g * 128;
    int cc = threadIdx.x;
    float a = 0.f;
    for (int j = 0; j < 128; j++) a = fmaf(eb[j], Wp[(size_t)j * 128 + cc], a);
    cb[l * 256 + kv * 128 + cc] = a;
}

// ============================ CSR construction =============================
__global__ void zero_i32(int* __restrict__ p, int n) {
    int i = blockIdx.x * 256 + threadIdx.x;
    if (i < n) p[i] = 0;
}
__global__ void hist_kernel(const int* __restrict__ dst, int E, int* __restrict__ deg) {
    int e = blockIdx.x * 256 + threadIdx.x;
    if (e < E) atomicAdd(&deg[dst[e]], 1);
}
__global__ __launch_bounds__(256) void exscan5(const int* __restrict__ deg0,
                                               int* __restrict__ off0,
                                               int* __restrict__ cursor0, int n) {
    int g = blockIdx.x;
    const int* deg = deg0 + (size_t)g * n;
    int* off = off0 + (size_t)g * (n + 1);
    int* cursor = cursor0 + (size_t)g * n;
    __shared__ int wsum[4];
    __shared__ int carry;
    int tid = threadIdx.x, lane = tid & 63, w = tid >> 6;
    if (tid == 0) carry = 0;
    __syncthreads();
    for (int base = 0; base < n; base += 256) {
        int v = (base + tid < n) ? deg[base + tid] : 0;
        int incl = v;
        for (int d = 1; d < 64; d <<= 1) {
            int t = __shfl_up(incl, d, 64);
            if (lane >= d) incl += t;
        }
        if (lane == 63) wsum[w] = incl;
        __syncthreads();
        int woff = 0;
        for (int i = 0; i < w; i++) woff += wsum[i];
        int total = wsum[0] + wsum[1] + wsum[2] + wsum[3];
        int excl = carry + woff + incl - v;
        if (base + tid < n) { off[base + tid] = excl; cursor[base + tid] = excl; }
        __syncthreads();
        if (tid == 0) carry += total;
        __syncthreads();
    }
    if (threadIdx.x == 0) off[n] = carry;
}
__global__ void scatter_kernel(const int* __restrict__ dst, int E,
                               int* __restrict__ cursor, int* __restrict__ eids) {
    int e = blockIdx.x * 256 + threadIdx.x;
    if (e < E) { int p = atomicAdd(&cursor[dst[e]], 1); eids[p] = e; }
}
__global__ void sort_edges(const int* __restrict__ eid, const int* __restrict__ srcArr,
                           const float* __restrict__ attr, int aw, int E,
                           int* __restrict__ esrc, float4* __restrict__ eattr) {
    int pos = blockIdx.x * 256 + threadIdx.x;
    if (pos >= E) return;
    int e = eid[pos];
    esrc[pos] = srcArr[e];
    if (attr) {
        float4 v;
        v.x = attr[(size_t)e * aw + 0];
        v.y = attr[(size_t)e * aw + 1];
        v.z = (aw > 2) ? attr[(size_t)e * aw + 2] : 0.f;
        v.w = (aw > 3) ? attr[(size_t)e * aw + 3] : 0.f;
        eattr[pos] = v;
    }
}

// ====== degree-sorted dst order (DESCENDING): LDS counting sort, 33 bins ===
__global__ __launch_bounds__(256) void hist_deg2(const int* __restrict__ deg5, int n,
                                                 int* __restrict__ bh) {
    int g = blockIdx.y;
    const int* deg = deg5 + (size_t)g * n;
    __shared__ int lh[33];
    if (threadIdx.x < 33) lh[threadIdx.x] = 0;
    __syncthreads();
    int d = blockIdx.x * 256 + threadIdx.x;
    if (d < n) { int b = deg[d]; if (b > 32) b = 32; atomicAdd(&lh[b], 1); }
    __syncthreads();
    if (threadIdx.x < 33)
        bh[((size_t)g * NB_ + blockIdx.x) * 33 + threadIdx.x] = lh[threadIdx.x];
}
__global__ __launch_bounds__(64) void scan_bh(int* __restrict__ bh) {
    int g = blockIdx.x;
    int* p = bh + (size_t)g * NB_ * 33;
    __shared__ int tot[33], base[33];
    int bin = threadIdx.x;
    if (bin < 33) {
        int t = 0;
        for (int b = 0; b < NB_; b++) t += p[b * 33 + bin];
        tot[bin] = t;
    }
    __syncthreads();
    if (threadIdx.x == 0) {
        // DESCENDING degree order: heaviest bins get the lowest offsets so
        // the longest-running blocks are dispatched first (no heavy tail).
        int acc = 0;
        for (int i = 32; i >= 0; i--) { base[i] = acc; acc += tot[i]; }
    }
    __syncthreads();
    if (bin < 33) {
        int run = base[bin];
        for (int b = 0; b < NB_; b++) { int v = p[b * 33 + bin]; p[b * 33 + bin] = run; run += v; }
    }
}
__global__ __launch_bounds__(256) void scatter_ord2(const int* __restrict__ deg5, int n,
                                                    const int* __restrict__ bh,
                                                    int* __restrict__ dord5) {
    int g = blockIdx.y;
    const int* deg = deg5 + (size_t)g * n;
    int* dord = dord5 + (size_t)g * n;
    __shared__ int cur[33];
    if (threadIdx.x < 33)
        cur[threadIdx.x] = bh[((size_t)g * NB_ + blockIdx.x) * 33 + threadIdx.x];
    __syncthreads();
    int d = blockIdx.x * 256 + threadIdx.x;
    if (d < n) {
        int b = deg[d]; if (b > 32) b = 32;
        int p = atomicAdd(&cur[b], 1);
        dord[p] = d;
    }
}

// ====== prep_g: g[d][cp][h] = bf16( 0.25*sum_t Ck[cp][16h+t] q[d][16h+t] ) =
__global__ __launch_bounds__(256) void prep_g(const float* __restrict__ q,
                                              const float* __restrict__ cWl,
                                              const float* __restrict__ cbl,
                                              ushort* __restrict__ g,
                                              float* __restrict__ sb) {
    __shared__ float qs[8 * 132];
    int tid = threadIdx.x;
    int cp = tid & 127, hb = (tid >> 7) * 4;     // hb in {0,4}, wave-uniform
    float ck[64];
    {
        const float* csrc = cWl + (size_t)cp * 256 + hb * 16;
#pragma unroll
        for (int t4 = 0; t4 < 16; t4++) {
            float4 v = *(const float4*)(csrc + t4 * 4);
            ck[t4 * 4 + 0] = v.x; ck[t4 * 4 + 1] = v.y;
            ck[t4 * 4 + 2] = v.z; ck[t4 * 4 + 3] = v.w;
        }
    }
    int d0 = blockIdx.x * 8;
    {
        int dl = tid >> 5, col = (tid & 31) * 4;
        *(float4*)(qs + dl * 132 + col) = *(const float4*)(q + (size_t)(d0 + dl) * 128 + col);
    }
    __syncthreads();
#pragma unroll
    for (int dl = 0; dl < 8; dl++) {
        const float* qr = qs + dl * 132 + hb * 16;   // broadcast reads
        float a0 = 0.f, a1 = 0.f, a2 = 0.f, a3 = 0.f;
#pragma unroll
        for (int t = 0; t < 16; t++) {
            a0 = fmaf(ck[t],      qr[t],      a0);
            a1 = fmaf(ck[16 + t], qr[16 + t], a1);
            a2 = fmaf(ck[32 + t], qr[32 + t], a2);
            a3 = fmaf(ck[48 + t], qr[48 + t], a3);
        }
        ushort4 o = make_ushort4(f2bh(a0 * 0.25f), f2bh(a1 * 0.25f),
                                 f2bh(a2 * 0.25f), f2bh(a3 * 0.25f));
        *(ushort4*)(g + (size_t)(d0 + dl) * 1024 + cp * 8 + hb) = o;
    }
    if (tid < 64) {
        int dl = tid >> 3, h = tid & 7;
        const float* qr = qs + dl * 132 + h * 16;
        const float* cbr = cbl + h * 16;
        float a = 0.f;
#pragma unroll
        for (int t = 0; t < 16; t++) a = fmaf(cbr[t], qr[t], a);
        sb[(d0 + dl) * 8 + h] = a * 0.25f;
    }
}

// ===== fused attention + Cv epilogue: one wave per dst, writes agg =========
static constexpr int HS_ = 136;   // padded h-stride: conflict-free hstage access
__global__ __launch_bounds__(256) void attn_fact(const int* __restrict__ dord,
                                                 const int* __restrict__ off,
                                                 const int* __restrict__ esrc,
                                                 const float4* __restrict__ eattr,
                                                 const ushort* __restrict__ g,
                                                 const float* __restrict__ sb,
                                                 const float* __restrict__ eW1,
                                                 const float* __restrict__ eb1,
                                                 const float* __restrict__ q,
                                                 const ushort* __restrict__ kvp,
                                                 const float* __restrict__ cWl,
                                                 const float* __restrict__ cbl,
                                                 float* __restrict__ agg) {
    __shared__ float hw4[4 * 144];
    __shared__ float hstage[4][8 * HS_];
    __shared__ float vstage[4][128];
    __shared__ float dens2[4][8];
    __shared__ float part[2][4][128];
    __shared__ int sD[4];
    int w = threadIdx.x >> 6, l = threadIdx.x & 63;
    int i = l & 15, hlo = l >> 4;
    float* hw = hw4 + w * 144;   // [0..127] h_e, [128..135] w bcast
    int d = dord[blockIdx.x * 4 + w];
    int beg = off[d], end = off[d + 1];
    float q0 = q[(size_t)d * 128 + l] * 0.25f;
    float q1 = q[(size_t)d * 128 + 64 + l] * 0.25f;
    float gA[8], gB[8];
#pragma unroll
    for (int j = 0; j < 8; j++) {
        gA[j] = bh2f(g[(size_t)d * 1024 + (j * 16 + i) * 8 + hlo]);
        gB[j] = bh2f(g[(size_t)d * 1024 + (j * 16 + i) * 8 + hlo + 4]);
    }
    float sbA = sb[d * 8 + hlo], sbB = sb[d * 8 + 4 + hlo];
    float w1a[4], w1b[4];
#pragma unroll
    for (int j = 0; j < 4; j++) { w1a[j] = eW1[j * 128 + l]; w1b[j] = eW1[j * 128 + 64 + l]; }
    float ebA = eb1[l], ebB = eb1[64 + l];
    float dnA = 0.f, dnB = 0.f;
    float accL[8] = {}, accH[8] = {};
    float va0 = 0.f, va1 = 0.f;
    // 2-deep prefetch pipeline; keep raw ushorts (convert at use)
    float4 atA = make_float4(0.f, 0.f, 0.f, 0.f), atB = atA;
    ushort kA0 = 0, kA1 = 0, vA0 = 0, vA1 = 0;
    ushort kB0 = 0, kB1 = 0, vB0 = 0, vB1 = 0;
    auto LOADE = [&](int p, float4& at, ushort& ka, ushort& kb, ushort& va, ushort& vb) {
        int s = esrc[p]; at = eattr[p];
        const ushort* r = kvp + (size_t)s * 256;
        ka = r[l]; kb = r[64 + l];
        va = r[128 + l]; vb = r[192 + l];
    };
    if (beg < end) LOADE(beg, atA, kA0, kA1, vA0, vA1);
    if (beg + 1 < end) LOADE(beg + 1, atB, kB0, kB1, vB0, vB1);
    for (int pos = beg; pos < end; pos++) {
        float4 at = atA;
        ushort rk0 = kA0, rk1 = kA1, rv0 = vA0, rv1 = vA1;
        atA = atB; kA0 = kB0; kA1 = kB1; vA0 = vB0; vA1 = vB1;
        if (pos + 2 < end) LOADE(pos + 2, atB, kB0, kB1, vB0, vB1);
        float h0 = fmaxf(ebA + at.x * w1a[0] + at.y * w1a[1] + at.z * w1a[2] + at.w * w1a[3], 0.f);
        float h1 = fmaxf(ebB + at.x * w1b[0] + at.y * w1b[1] + at.z * w1b[2] + at.w * w1b[3], 0.f);
        hw[l] = h0; hw[64 + l] = h1;
        __builtin_amdgcn_wave_barrier();
        float pA = q0 * bh2f(rk0), pB = q1 * bh2f(rk1);
#pragma unroll
        for (int j = 0; j < 8; j++) {
            float hv = hw[j * 16 + i];
            pA = fmaf(hv, gA[j], pA);
            pB = fmaf(hv, gB[j], pB);
        }
#pragma unroll
        for (int msk = 1; msk < 16; msk <<= 1) {
            pA += __shfl_xor(pA, msk, 64);
            pB += __shfl_xor(pB, msk, 64);
        }
        // scores are provably tiny (|s| << 80): softmax without max-shift
        float wA = __expf(pA + sbA);
        float wB = __expf(pB + sbB);
        dnA += wA; dnB += wB;
        va0 = fmaf(wA, bh2f(rv0), va0);
        va1 = fmaf(wB, bh2f(rv1), va1);
        if (i == 0) { hw[128 + hlo] = wA; hw[132 + hlo] = wB; }
        __builtin_amdgcn_wave_barrier();
        float4 WA = *(float4*)(hw + 128), WB = *(float4*)(hw + 132);
#pragma unroll
        for (int j = 0; j < 4; j++) {
            float wa = ((const float*)&WA)[j];
            float wb = ((const float*)&WB)[j];
            accL[j]     = fmaf(wa, h0, accL[j]);
            accH[j]     = fmaf(wa, h1, accH[j]);
            accL[4 + j] = fmaf(wb, h0, accL[4 + j]);
            accH[4 + j] = fmaf(wb, h1, accH[4 + j]);
        }
    }
    // stage per-dst state to LDS (padded h-stride HS_ = conflict-free)
#pragma unroll
    for (int h = 0; h < 8; h++) {
        hstage[w][h * HS_ + l]      = accL[h];
        hstage[w][h * HS_ + 64 + l] = accH[h];
    }
    vstage[w][l] = va0; vstage[w][64 + l] = va1;
    if (i == 0) { dens2[w][hlo] = dnA; dens2[w][4 + hlo] = dnB; }
    if (l == 0) sD[w] = d;
    __syncthreads();
    // epilogue pass 1: cp split across 2 halves; each Cv element loaded once,
    // used for all 4 dsts -> 64-deep load chain, 4 FMA per load.
    {
        int cc = threadIdx.x & 127, h2 = threadIdx.x >> 7;
        int hh = cc >> 4;
        int cp0 = h2 * 64;
        const float* cvp = cWl + 128 + cc + (size_t)cp0 * 256;
        const float* h0p = &hstage[0][hh * HS_ + cp0];
        const float* h1p = &hstage[1][hh * HS_ + cp0];
        const float* h2p = &hstage[2][hh * HS_ + cp0];
        const float* h3p = &hstage[3][hh * HS_ + cp0];
        float p0 = 0.f, p1 = 0.f, p2 = 0.f, p3 = 0.f;
#pragma unroll 8
        for (int cp = 0; cp < 64; cp++) {
            float cv = cvp[(size_t)cp * 256];
            p0 = fmaf(h0p[cp], cv, p0);
            p1 = fmaf(h1p[cp], cv, p1);
            p2 = fmaf(h2p[cp], cv, p2);
            p3 = fmaf(h3p[cp], cv, p3);
        }
        part[h2][0][cc] = p0; part[h2][1][cc] = p1;
        part[h2][2][cc] = p2; part[h2][3][cc] = p3;
    }
    __syncthreads();
    // epilogue pass 2: combine halves, normalize, write 2 dsts per thread
    {
        int cc = threadIdx.x & 127, h2 = threadIdx.x >> 7;
        int hh = cc >> 4;
        float cvb = cbl[128 + cc];
#pragma unroll
        for (int t = 0; t < 2; t++) {
            int ds = h2 * 2 + t;
            float dn = dens2[ds][hh];
            float inv = 1.f / (dn + 1e-9f);
            float cf = dn * inv;
            float a = part[0][ds][cc] + part[1][ds][cc];
            agg[(size_t)sD[ds] * 128 + cc] = (vstage[ds][cc] + a) * inv + cvb * cf;
        }
    }
}

// ===== plain fused attention (no-max softmax, bf16 kv, deg-sorted) =========
__global__ __launch_bounds__(256) void attn_plain(const int* __restrict__ dord,
                                                  const int* __restrict__ off,
                                                  const int* __restrict__ esrc,
                                                  const float* __restrict__ q,
                                                  const ushort* __restrict__ kvp,
                                                  float* __restrict__ agg) {
    int lane = threadIdx.x & 63;
    int d = dord[blockIdx.x * 4 + (threadIdx.x >> 6)];
    int beg = off[d], end = off[d + 1];
    float q0 = q[(size_t)d * 128 + lane] * 0.25f;
    float q1 = q[(size_t)d * 128 + 64 + lane] * 0.25f;
    float den0 = 0.f, den1 = 0.f, acc0 = 0.f, acc1 = 0.f;
    ushort kA0 = 0, kA1 = 0, vA0 = 0, vA1 = 0;
    ushort kB0 = 0, kB1 = 0, vB0 = 0, vB1 = 0;
    auto LOADE = [&](int p, ushort& ka, ushort& kb, ushort& va, ushort& vb) {
        int s = esrc[p];
        const ushort* r = kvp + (size_t)s * 256;
        ka = r[lane]; kb = r[64 + lane];
        va = r[128 + lane]; vb = r[192 + lane];
    };
    if (beg < end) LOADE(beg, kA0, kA1, vA0, vA1);
    if (beg + 1 < end) LOADE(beg + 1, kB0, kB1, vB0, vB1);
    for (int pos = beg; pos < end; pos++) {
        ushort rk0 = kA0, rk1 = kA1, rv0 = vA0, rv1 = vA1;
        kA0 = kB0; kA1 = kB1; vA0 = vB0; vA1 = vB1;
        if (pos + 2 < end) LOADE(pos + 2, kB0, kB1, vB0, vB1);
        float p0 = q0 * bh2f(rk0), p1 = q1 * bh2f(rk1);
#pragma unroll
        for (int msk = 1; msk < 16; msk <<= 1) {
            p0 += __shfl_xor(p0, msk, 64);
            p1 += __shfl_xor(p1, msk, 64);
        }
        float w0 = __expf(p0), w1 = __expf(p1);
        den0 += w0; den1 += w1;
        acc0 = fmaf(w0, bh2f(rv0), acc0);
        acc1 = fmaf(w1, bh2f(rv1), acc1);
    }
    agg[(size_t)d * 128 + lane]      = acc0 / (den0 + 1e-9f);
    agg[(size_t)d * 128 + 64 + lane] = acc1 / (den1 + 1e-9f);
}

// ======================= small glue kernels ================================
__global__ void mode_init(float* __restrict__ m, const float* __restrict__ mt) {
    int idx = blockIdx.x * 256 + threadIdx.x;
    if (idx >= M_ * H_) return;
    int node = idx >> 7, c = idx & 127;
    m[idx] = mt[(node % K_) * H_ + c];
}
__global__ void extract_last(const float* __restrict__ m, float* __restrict__ out) {
    int idx = blockIdx.x * 256 + threadIdx.x;
    if (idx >= AK_ * H_) return;
    int row = idx >> 7, c = idx & 127;
    int a = row / K_, k = row - a * K_;
    int node = (a * T_ + (T_ - 1)) * K_ + k;
    out[idx] = m[(size_t)node * H_ + c];
}
__global__ void add_anchor(float* __restrict__ m, const float* __restrict__ anchor) {
    int idx = blockIdx.x * 256 + threadIdx.x;
    if (idx >= M_ * H_) return;
    int node = idx >> 7, c = idx & 127;
    int a = node / (T_ * K_), k = node % K_;
    m[idx] += anchor[(size_t)(a * K_ + k) * H_ + c];
}

// ============================ host launch ==================================
extern "C" void kernel_launch(void* const* d_in, const int* in_sizes, int n_in,
                              void* d_out, int out_size, void* d_ws, size_t ws_size,
                              hipStream_t stream) {
    const float* a_input     = (const float*)d_in[0];
    const float* l_embs      = (const float*)d_in[1];
    const float* mode_tokens = (const float*)d_in[2];
    const float* emb_W1 = (const float*)d_in[3];
    const float* emb_b1 = (const float*)d_in[4];
    const float* emb_W2 = (const float*)d_in[5];
    const float* emb_b2 = (const float*)d_in[6];
    const float* ga_Wq  = (const float*)d_in[7];
    const float* ga_Wk  = (const float*)d_in[8];
    const float* ga_Wv  = (const float*)d_in[9];
    const float* ga_Wo  = (const float*)d_in[10];
    const float* ga_Wke = (const float*)d_in[11];
    const float* ga_Wve = (const float*)d_in[12];
    const float* ga_g1  = (const float*)d_in[13];
    const float* ga_b1  = (const float*)d_in[14];
    const float* ga_g2  = (const float*)d_in[15];
    const float* ga_b2  = (const float*)d_in[16];
    const float* ga_fW1 = (const float*)d_in[17];
    const float* ga_fb1 = (const float*)d_in[18];
    const float* ga_fW2 = (const float*)d_in[19];
    const float* ga_fb2 = (const float*)d_in[20];
    const float* tp_W1 = (const float*)d_in[21];
    const float* tp_b1 = (const float*)d_in[22];
    const float* tp_W2 = (const float*)d_in[23];
    const float* tp_b2 = (const float*)d_in[24];
    const float* pa_W1 = (const float*)d_in[25];
    const float* pa_b1 = (const float*)d_in[26];
    const float* pa_W2 = (const float*)d_in[27];
    const float* pa_b2 = (const float*)d_in[28];
    const float* tr_W1 = (const float*)d_in[29];
    const float* tr_b1 = (const float*)d_in[30];
    const float* tr_W2 = (const float*)d_in[31];
    const float* tr_b2 = (const float*)d_in[32];
    const float* attrs[4] = { (const float*)d_in[33], (const float*)d_in[34],
                              (const float*)d_in[35], (const float*)d_in[36] };
    const int* eis[5] = { (const int*)d_in[37], (const int*)d_in[38], (const int*)d_in[39],
                          (const int*)d_in[40], (const int*)d_in[41] };
    int Es[5];
    int Emax = 0;
    for (int i = 0; i < 5; i++) { Es[i] = in_sizes[37 + i] / 2; if (Es[i] > Emax) Emax = Es[i]; }

    size_t off = 0;
    auto alloc = [&](size_t nbytes) -> char* {
        char* p = (char*)d_ws + off;
        off += ((nbytes + 255) / 256) * 256;
        return p;
    };
    float* cW     = (float*)alloc((size_t)NL_ * 128 * 256 * 4);
    float* cb     = (float*)alloc((size_t)NL_ * 256 * 4);
    ushort* wbh   = (ushort*)alloc((size_t)NL_ * WLAY * 2);
    ushort* wbl   = (ushort*)alloc((size_t)NL_ * WLAY * 2);
    float* a_embs = (float*)alloc((size_t)AT_ * H_ * 4);
    float* m      = (float*)alloc((size_t)M_ * H_ * 4);
    float* q      = (float*)alloc((size_t)M_ * H_ * 4);
    ushort* kvb   = (ushort*)alloc((size_t)M_ * 256 * 2);    // bf16 k|v fused
    float* agg    = (float*)alloc((size_t)M_ * H_ * 4);
    float* big    = (float*)alloc((size_t)M_ * FF_ * 4);     // FFN hidden
    ushort* gbuf  = (ushort*)alloc((size_t)M_ * 1024 * 2);   // bf16 g [d][cp][h]
    float* sb     = (float*)alloc((size_t)M_ * 8 * 4);
    float* muM    = (float*)alloc((size_t)M_ * 4);
    float* rsM    = (float*)alloc((size_t)M_ * 4);
    float* muA    = (float*)alloc((size_t)AT_ * 4);
    float* rsA    = (float*)alloc((size_t)AT_ * 4);
    float* muL    = (float*)alloc((size_t)L_ * 4);
    float* rsL    = (float*)alloc((size_t)L_ * 4);
    int* csr_off  = (int*)alloc((size_t)5 * (M_ + 1) * 4);
    int* csr_eid  = (int*)alloc((size_t)5 * Emax * 4);
    int* esrc     = (int*)alloc((size_t)5 * Emax * 4);
    float4* eattr = (float4*)alloc((size_t)4 * Emax * 16);
    int* deg5     = (int*)alloc((size_t)5 * M_ * 4);
    int* cursor5  = (int*)alloc((size_t)5 * M_ * 4);
    int* dord5    = (int*)alloc((size_t)5 * M_ * 4);
    int* bh5      = (int*)alloc((size_t)5 * NB_ * 33 * 4);
    float* mlast  = (float*)alloc((size_t)AK_ * H_ * 4);
    float* hbuf   = (float*)alloc((size_t)AK_ * H_ * 4);
    float* anchor = (float*)alloc((size_t)AK_ * H_ * 4);
    (void)ws_size; (void)n_in;

    float* outp = (float*)d_out;

    // ---- CSR + sorted src/attr + degree-sorted dst order for 5 graphs ----
    zero_i32<<<(5 * M_ + 255) / 256, 256, 0, stream>>>(deg5, 5 * M_);
    for (int gI = 0; gI < 5; gI++)
        hist_kernel<<<(Es[gI] + 255) / 256, 256, 0, stream>>>(eis[gI] + Es[gI], Es[gI], deg5 + (size_t)gI * M_);
    exscan5<<<5, 256, 0, stream>>>(deg5, csr_off, cursor5, M_);
    for (int gI = 0; gI < 5; gI++)
        scatter_kernel<<<(Es[gI] + 255) / 256, 256, 0, stream>>>(eis[gI] + Es[gI], Es[gI],
            cursor5 + (size_t)gI * M_, csr_eid + (size_t)gI * Emax);
    for (int gI = 0; gI < 5; gI++) {
        int aw = (gI == 0 || gI == 2) ? 4 : (gI == 4 ? 0 : 3);
        sort_edges<<<(Es[gI] + 255) / 256, 256, 0, stream>>>(
            csr_eid + (size_t)gI * Emax, eis[gI], (gI < 4) ? attrs[gI] : nullptr, aw, Es[gI],
            esrc + (size_t)gI * Emax, eattr + (size_t)gI * Emax);
    }
    hist_deg2<<<dim3(NB_, 5), 256, 0, stream>>>(deg5, M_, bh5);
    scan_bh<<<5, 64, 0, stream>>>(bh5);
    scatter_ord2<<<dim3(NB_, 5), 256, 0, stream>>>(deg5, M_, bh5, dord5);

    // ---- weight prep ----
    prep_w<<<dim3(192, 10), 256, 0, stream>>>(ga_Wq, ga_Wk, ga_Wv, ga_Wo, ga_fW1, ga_fW2, wbh, wbl);
    combine_fast<<<16, 256, 0, stream>>>(emb_W2, ga_Wke, ga_Wve, cW);
    combine_bias<<<16, 128, 0, stream>>>(emb_b2, ga_Wke, ga_Wve, cb);

    // ---- embeddings / init ----
    small_gemm<1, false><<<(AT_ * H_ + 255) / 256, 256, 0, stream>>>(a_input, emb_W1, emb_b1, nullptr, big, AT_, 5, H_);
    small_gemm<0, false><<<(AT_ * H_ + 255) / 256, 256, 0, stream>>>(big, emb_W2, emb_b2, nullptr, a_embs, AT_, H_, H_);
    mode_init<<<(M_ * H_ + 255) / 256, 256, 0, stream>>>(m, mode_tokens);
    ln_stats<<<M_ / 4, 256, 0, stream>>>(m, muM, rsM, M_);
    ln_stats<<<AT_ / 4, 256, 0, stream>>>(a_embs, muA, rsA, AT_);
    ln_stats<<<L_ / 4, 256, 0, stream>>>(l_embs, muL, rsL, L_);

    struct Cfg { const float* srcX; const float* muS; const float* rsS; int n_src; int gi; bool hasE; };
    Cfg cfgs[10] = {
        { a_embs, muA, rsA, AT_, 0, true }, { l_embs, muL, rsL, L_, 1, true },
        { nullptr, nullptr, nullptr, M_, 2, true }, { nullptr, nullptr, nullptr, M_, 3, true },
        { nullptr, nullptr, nullptr, M_, 4, false },
        { a_embs, muA, rsA, AT_, 0, true }, { l_embs, muL, rsL, L_, 1, true },
        { nullptr, nullptr, nullptr, M_, 2, true }, { nullptr, nullptr, nullptr, M_, 3, true },
        { nullptr, nullptr, nullptr, M_, 4, false },
    };

    for (int l = 0; l < 10; l++) {
        const Cfg& cf = cfgs[l];
        const int* offg = csr_off + cf.gi * (M_ + 1);
        const int* esrcg = esrc + (size_t)cf.gi * Emax;
        const float4* eattrg = eattr + (size_t)cf.gi * Emax;
        const int* dordg = dord5 + (size_t)cf.gi * M_;
        const float* g1 = ga_g1 + l * H_; const float* b1 = ga_b1 + l * H_;
        size_t wb = (size_t)l * WLAY;

        // muM/rsM currently hold LN1 stats of m (from prev FFN2 STATS / init)
        if (cf.srcX) {
            mgemm<0, false, 0, true, false><<<dim3(M_ / 128, 1), 256, 0, stream>>>(
                m, wbh + wb, wbl + wb, nullptr, nullptr, q, nullptr,
                muM, rsM, g1, b1, nullptr, nullptr, M_, 128, 128);
            mgemm<0, false, 1, true, false><<<dim3(cf.n_src / 128, 2), 256, 0, stream>>>(
                cf.srcX, wbh + wb + 16384, wbl + wb + 16384, nullptr, nullptr, nullptr, kvb,
                cf.muS, cf.rsS, g1, b1, nullptr, nullptr, cf.n_src, 128, 256);
        } else {
            mgemm<0, false, 2, true, false><<<dim3(M_ / 128, 3), 256, 0, stream>>>(
                m, wbh + wb, wbl + wb, nullptr, nullptr, q, kvb,
                muM, rsM, g1, b1, nullptr, nullptr, M_, 128, 384);
        }

        if (cf.hasE) {
            int gg = (l < 5) ? l + 1 : l - 4;
            const float* eW1g = emb_W1 + (size_t)gg * 5 * H_;
            const float* eb1g = emb_b1 + (size_t)gg * H_;
            prep_g<<<M_ / 8, 256, 0, stream>>>(q, cW + (size_t)l * 32768, cb + l * 256, gbuf, sb);
            attn_fact<<<M_ / 4, 256, 0, stream>>>(dordg, offg, esrcg, eattrg, gbuf, sb, eW1g, eb1g,
                                                  q, kvb, cW + (size_t)l * 32768, cb + l * 256, agg);
        } else {
            attn_plain<<<M_ / 4, 256, 0, stream>>>(dordg, offg, esrcg, q, kvb, agg);
        }

        // m += agg @ Wo   (+ LN2 stats fused)
        mgemm<0, true, 0, false, true><<<dim3(M_ / 128, 1), 256, 0, stream>>>(
            agg, wbh + wb + 49152, wbl + wb + 49152, nullptr, m, m, nullptr,
            nullptr, nullptr, nullptr, nullptr, muM, rsM, M_, 128, 128);
        // FFN with fused LN2
        mgemm<1, false, 0, true, false><<<dim3(M_ / 128, 4), 256, 0, stream>>>(
            m, wbh + wb + 65536, wbl + wb + 65536, ga_fb1 + l * FF_, nullptr, big, nullptr,
            muM, rsM, ga_g2 + l * H_, ga_b2 + l * H_, nullptr, nullptr, M_, 128, 512);
        // FFN2 (+ next-layer LN1 stats fused)
        mgemm<0, true, 0, false, true><<<dim3(M_ / 128, 1), 256, 0, stream>>>(
            big, wbh + wb + 131072, wbl + wb + 131072, ga_fb2 + l * H_, m, m, nullptr,
            nullptr, nullptr, nullptr, nullptr, muM, rsM, M_, 512, 128);

        if (l == 4) {
            extract_last<<<(AK_ * H_ + 255) / 256, 256, 0, stream>>>(m, mlast);
            small_gemm<1, false><<<(AK_ * H_ + 255) / 256, 256, 0, stream>>>(mlast, tp_W1, tp_b1, nullptr, hbuf, AK_, H_, H_);
            small_gemm<0, false><<<(AK_ * P2F + 255) / 256, 256, 0, stream>>>(hbuf, tp_W2, tp_b2, nullptr, outp, AK_, H_, P2F);
            small_gemm<1, false><<<(AK_ * H_ + 255) / 256, 256, 0, stream>>>(outp, pa_W1, pa_b1, nullptr, hbuf, AK_, P2F, H_);
            small_gemm<0, false><<<(AK_ * H_ + 255) / 256, 256, 0, stream>>>(hbuf, pa_W2, pa_b2, nullptr, anchor, AK_, H_, H_);
            add_anchor<<<(M_ * H_ + 255) / 256, 256, 0, stream>>>(m, anchor);
            ln_stats<<<M_ / 4, 256, 0, stream>>>(m, muM, rsM, M_);   // m changed
        }
    }

    extract_last<<<(AK_ * H_ + 255) / 256, 256, 0, stream>>>(m, mlast);
    small_gemm<1, false><<<(AK_ * H_ + 255) / 256, 256, 0, stream>>>(mlast, tr_W1, tr_b1, nullptr, hbuf, AK_, H_, H_);
    small_gemm<0, true><<<(AK_ * P2F + 255) / 256, 256, 0, stream>>>(hbuf, tr_W2, tr_b2, outp, outp + AK_ * P2F, AK_, H_, P2F);
}